// Round 1
// 2726.456 us; speedup vs baseline: 1.9216x; 1.9216x over previous
//
#include <hip/hip_runtime.h>
#include <math.h>

// Problem constants
#define Bv 2
#define Lv 1024
#define Dv 512
#define Hv 8
#define DH 64
#define Fv 2048
#define NBv 6
#define Vv 32000
#define Mv (Bv*Lv)          // 2048 rows
#define NEGINF -1e10f

typedef __attribute__((ext_vector_type(8))) short short8;   // 8 bf16
typedef __attribute__((ext_vector_type(4))) short short4v;  // 4 bf16
typedef __attribute__((ext_vector_type(4))) float floatx4;
typedef __attribute__((address_space(1))) const void gvoid;
typedef __attribute__((address_space(3))) void svoid;

__device__ __forceinline__ short f2bf(float f) {
    union { float f; unsigned u; } v; v.f = f;
    unsigned r = v.u + 0x7fffu + ((v.u >> 16) & 1u);   // RNE
    return (short)(r >> 16);
}

// ---------------------------------------------------------------------------
// Embedding + sinusoidal positional encoding (fp32 h)
__global__ __launch_bounds__(256)
void embed_kernel(const int* __restrict__ xi, const float* __restrict__ emb,
                  float* __restrict__ h)
{
    const int row = blockIdx.x;
    const int l   = row & (Lv - 1);
    const int tok = xi[row];
    const int tid = threadIdx.x;
#pragma unroll
    for (int s = 0; s < 2; ++s) {
        const int d  = tid + s * 256;
        const int dd = d & 255;
        const float freq = powf(10000.f, (float)dd * (1.f / 256.f));
        const float arg  = (float)l / freq;
        const float pe   = (d < 256) ? sinf(arg) : cosf(arg);
        h[(size_t)row * Dv + d] = emb[(size_t)tok * Dv + d] * 22.62741699796952f + pe;
    }
}

// ---------------------------------------------------------------------------
// fp32 -> bf16 convert (for ctx)
__global__ __launch_bounds__(256)
void cvt_kernel(const float* __restrict__ X, short* __restrict__ Y)
{
    const int i = (blockIdx.x * 256 + threadIdx.x) * 4;
    const float4 v = *(const float4*)(X + i);
    short4v p; p.x = f2bf(v.x); p.y = f2bf(v.y); p.z = f2bf(v.z); p.w = f2bf(v.w);
    *(short4v*)(Y + i) = p;
}

// ---------------------------------------------------------------------------
// LayerNorm: one block per row, 256 threads, D=512; bf16 output
__global__ __launch_bounds__(256)
void ln_kernel(const float* __restrict__ X, const float* __restrict__ g,
               const float* __restrict__ bta, short* __restrict__ Y)
{
    const int row = blockIdx.x, tid = threadIdx.x;
    const float* xr = X + (size_t)row * Dv;
    const float x0 = xr[tid], x1 = xr[tid + 256];
    __shared__ float red[4];

    float s = x0 + x1;
#pragma unroll
    for (int off = 32; off; off >>= 1) s += __shfl_xor(s, off);
    if ((tid & 63) == 0) red[tid >> 6] = s;
    __syncthreads();
    const float mean = (red[0] + red[1] + red[2] + red[3]) * (1.f / Dv);
    __syncthreads();

    const float d0 = x0 - mean, d1 = x1 - mean;
    float v = d0 * d0 + d1 * d1;
#pragma unroll
    for (int off = 32; off; off >>= 1) v += __shfl_xor(v, off);
    if ((tid & 63) == 0) red[tid >> 6] = v;
    __syncthreads();
    const float var  = (red[0] + red[1] + red[2] + red[3]) * (1.f / Dv);
    const float rstd = rsqrtf(var + 1e-6f);

    Y[(size_t)row * Dv + tid]       = f2bf(d0 * rstd * g[tid]       + bta[tid]);
    Y[(size_t)row * Dv + tid + 256] = f2bf(d1 * rstd * g[tid + 256] + bta[tid + 256]);
}

// ---------------------------------------------------------------------------
// bf16 MFMA GEMM. A: bf16 [M,K] rm. B: fp32, BT? [N,K] : [K,N] rm (converted
// to bf16 during LDS staging). C = A@B (+bias) (+residual fp32) (relu?).
// BM=128, BK=32, block 256 = 4 waves (2x2), wave tile 64 x BN/2,
// frags 4 x (BN/32) of 16x16x32.
template <int BN, bool BT, bool OUTBF>
__global__ __launch_bounds__(256)
void mgemm(const short* __restrict__ A, const float* __restrict__ B,
           void* __restrict__ Cp, int M, int N, int K,
           const float* __restrict__ bias,
           const float* __restrict__ residual, int relu)
{
    constexpr int BM = 128, BK = 32;
    constexpr int NF = BN / 32;
    __shared__ short As[BM * BK];
    __shared__ short Bs[BN * BK];
    const int tid  = threadIdx.x;
    const int wave = tid >> 6, lane = tid & 63;
    const int wm = wave & 1, wn = wave >> 1;
    const int quad = lane >> 4, l16 = lane & 15;
    const int m0 = blockIdx.y * BM, n0 = blockIdx.x * BN;

    floatx4 acc[4][NF];
#pragma unroll
    for (int i = 0; i < 4; ++i)
#pragma unroll
        for (int j = 0; j < NF; ++j)
            acc[i][j] = (floatx4){0.f, 0.f, 0.f, 0.f};

    for (int k0 = 0; k0 < K; k0 += BK) {
        __syncthreads();
        // ---- A staging: 2 x 16B per thread via global_load_lds ----
#pragma unroll
        for (int s = 0; s < 2; ++s) {
            const int c = s * 256 + tid;             // chunk = 16B = 8 bf16
            const int row = c >> 2, kp = (c & 3) << 3;
            const short* gp = A + (size_t)(m0 + row) * K + k0 + kp;
            __builtin_amdgcn_global_load_lds((gvoid*)gp, (svoid*)((char*)As + c * 16),
                                             16, 0, 0);
        }
        // ---- B staging: fp32 -> bf16, Bs layout [n][k] ----
        if (!BT) {
            constexpr int QN = BN / 4;               // n-quads
            const int qn = tid % QN, kq = tid / QN;
            if (kq < 8) {
                const float* gp = B + (size_t)(k0 + kq * 4) * N + n0 + qn * 4;
                const float4 r0 = *(const float4*)(gp);
                const float4 r1 = *(const float4*)(gp + N);
                const float4 r2 = *(const float4*)(gp + 2 * (size_t)N);
                const float4 r3 = *(const float4*)(gp + 3 * (size_t)N);
                short4v p;
                p.x = f2bf(r0.x); p.y = f2bf(r1.x); p.z = f2bf(r2.x); p.w = f2bf(r3.x);
                *(short4v*)&Bs[(qn * 4 + 0) * BK + kq * 4] = p;
                p.x = f2bf(r0.y); p.y = f2bf(r1.y); p.z = f2bf(r2.y); p.w = f2bf(r3.y);
                *(short4v*)&Bs[(qn * 4 + 1) * BK + kq * 4] = p;
                p.x = f2bf(r0.z); p.y = f2bf(r1.z); p.z = f2bf(r2.z); p.w = f2bf(r3.z);
                *(short4v*)&Bs[(qn * 4 + 2) * BK + kq * 4] = p;
                p.x = f2bf(r0.w); p.y = f2bf(r1.w); p.z = f2bf(r2.w); p.w = f2bf(r3.w);
                *(short4v*)&Bs[(qn * 4 + 3) * BK + kq * 4] = p;
            }
        } else {
#pragma unroll
            for (int f = 0; f < BN / 32; ++f) {
                const int gidx = f * 256 + tid;      // float4 index
                const int n = gidx >> 3, q = gidx & 7;
                const float4 r = *(const float4*)(B + (size_t)(n0 + n) * K + k0 + q * 4);
                short4v p; p.x = f2bf(r.x); p.y = f2bf(r.y); p.z = f2bf(r.z); p.w = f2bf(r.w);
                *(short4v*)&Bs[n * BK + q * 4] = p;
            }
        }
        __syncthreads();
        // ---- compute: one K=32 MFMA per (mi,ni) ----
        short8 af[4];
#pragma unroll
        for (int mi = 0; mi < 4; ++mi)
            af[mi] = *(short8*)&As[(wm * 64 + mi * 16 + l16) * BK + quad * 8];
#pragma unroll
        for (int ni = 0; ni < NF; ++ni) {
            const short8 bfr = *(short8*)&Bs[(wn * (BN / 2) + ni * 16 + l16) * BK + quad * 8];
#pragma unroll
            for (int mi = 0; mi < 4; ++mi)
                acc[mi][ni] = __builtin_amdgcn_mfma_f32_16x16x32_bf16(af[mi], bfr, acc[mi][ni], 0, 0, 0);
        }
    }

    // ---- epilogue ----
#pragma unroll
    for (int mi = 0; mi < 4; ++mi)
#pragma unroll
        for (int ni = 0; ni < NF; ++ni)
#pragma unroll
            for (int r = 0; r < 4; ++r) {
                const int m = m0 + wm * 64 + mi * 16 + quad * 4 + r;
                const int n = n0 + wn * (BN / 2) + ni * 16 + l16;
                float v = acc[mi][ni][r];
                if (bias)     v += bias[n];
                if (residual) v += residual[(size_t)m * N + n];
                if (relu)     v = fmaxf(v, 0.f);
                if (OUTBF) ((short*)Cp)[(size_t)m * N + n] = f2bf(v);
                else       ((float*)Cp)[(size_t)m * N + n] = v;
            }
}

// ---------------------------------------------------------------------------
// Flash attention, bf16 MFMA path.  O = softmax(Q K^T / 8 (+causal)) V.
// Q,K,V,O: bf16 [B, L, D] with head offset h*64.
// grid (L/64, H, B); block 256 = 4 waves; each wave owns 16 query rows.
// KV tile = 64 keys.  K staged [j][d] (pad 72), V staged transposed [d][j]
// with XOR swizzle j ^= ((d>>3)&7)<<3 to kill transpose-write bank conflicts.
// Online softmax: per-lane partial sums, row state (m,s) per 16-lane group.
__global__ __launch_bounds__(256)
void attn_mfma(const short* __restrict__ Qp, const short* __restrict__ Kp,
               const short* __restrict__ Vp, short* __restrict__ Op, int causal)
{
    constexpr int PK = 72;                 // row pad: 144 B -> <=2-way conflicts
    __shared__ short Ks[64 * PK];
    __shared__ short Vs[64 * PK];          // transposed: Vs[d][j^swz]
    __shared__ short Ps[4][16 * PK];       // per-wave P re-fragment buffer
    const int tid  = threadIdx.x;
    const int wave = tid >> 6, lane = tid & 63;
    const int quad = lane >> 4, l16 = lane & 15;
    const int hh = blockIdx.y, bb = blockIdx.z;
    const int q0 = blockIdx.x * 64;
    const size_t base = (size_t)bb * Lv * Dv + (size_t)hh * DH;

    // Q fragments (A operand): lane -> row l16 of wave's 16 rows, k = quad*8..
    short8 aq[2];
    {
        const short* qp = Qp + base + (size_t)(q0 + wave * 16 + l16) * Dv + quad * 8;
        aq[0] = *(const short8*)qp;
        aq[1] = *(const short8*)(qp + 32);
    }

    floatx4 o[4];
#pragma unroll
    for (int i = 0; i < 4; ++i) o[i] = (floatx4){0.f, 0.f, 0.f, 0.f};
    float mrow[4] = {-3.4e38f, -3.4e38f, -3.4e38f, -3.4e38f};
    float srow[4] = {0.f, 0.f, 0.f, 0.f};

    const int ntiles = causal ? (q0 / 64 + 1) : (Lv / 64);

    for (int t = 0; t < ntiles; ++t) {
        const int j0 = t * 64;
        __syncthreads();
        // ---- stage K [j][d] and V transposed [d][j^swz] ----
#pragma unroll
        for (int s = 0; s < 2; ++s) {
            const int c = s * 256 + tid;
            const int j = c >> 3, off = (c & 7) * 8;
            const size_t grow = base + (size_t)(j0 + j) * Dv + off;
            *(short8*)&Ks[j * PK + off] = *(const short8*)(Kp + grow);
            const short8 v = *(const short8*)(Vp + grow);
            const int jx = j ^ ((c & 7) << 3);     // swz = ((d>>3)&7)<<3, d=off+e
#pragma unroll
            for (int e = 0; e < 8; ++e)
                Vs[(off + e) * PK + jx] = v[e];
        }
        __syncthreads();

        // ---- S = Q K^T (4 col-frags of 16) ----
        floatx4 sf[4];
#pragma unroll
        for (int nf = 0; nf < 4; ++nf) {
            const short8 bk0 = *(const short8*)&Ks[(nf * 16 + l16) * PK + quad * 8];
            const short8 bk1 = *(const short8*)&Ks[(nf * 16 + l16) * PK + 32 + quad * 8];
            floatx4 z = (floatx4){0.f, 0.f, 0.f, 0.f};
            z = __builtin_amdgcn_mfma_f32_16x16x32_bf16(aq[0], bk0, z, 0, 0, 0);
            z = __builtin_amdgcn_mfma_f32_16x16x32_bf16(aq[1], bk1, z, 0, 0, 0);
            sf[nf] = z;
        }

        // ---- scale + causal mask (diagonal tile only) ----
        const bool mask = causal && (j0 == q0);
#pragma unroll
        for (int nf = 0; nf < 4; ++nf) {
            const int jabs = j0 + nf * 16 + l16;
#pragma unroll
            for (int r = 0; r < 4; ++r) {
                float v = sf[nf][r] * 0.125f;
                if (mask && jabs > q0 + wave * 16 + quad * 4 + r) v = NEGINF;
                sf[nf][r] = v;
            }
        }

        // ---- online softmax update (row = quad*4 + r, reduce over 16 lanes) ----
#pragma unroll
        for (int r = 0; r < 4; ++r) {
            float v = fmaxf(fmaxf(sf[0][r], sf[1][r]), fmaxf(sf[2][r], sf[3][r]));
            v = fmaxf(v, __shfl_xor(v, 1));
            v = fmaxf(v, __shfl_xor(v, 2));
            v = fmaxf(v, __shfl_xor(v, 4));
            v = fmaxf(v, __shfl_xor(v, 8));
            const float mnew = fmaxf(mrow[r], v);
            const float corr = __expf(mrow[r] - mnew);
            mrow[r] = mnew;
            srow[r] *= corr;
#pragma unroll
            for (int nf = 0; nf < 4; ++nf) o[nf][r] *= corr;
        }

        // ---- P = exp(S - m) -> bf16, write to per-wave LDS for re-fragment ----
#pragma unroll
        for (int nf = 0; nf < 4; ++nf) {
#pragma unroll
            for (int r = 0; r < 4; ++r) {
                const float pv = __expf(sf[nf][r] - mrow[r]);
                srow[r] += pv;                      // per-lane partial row sum
                Ps[wave][(quad * 4 + r) * PK + nf * 16 + l16] = f2bf(pv);
            }
        }
        __builtin_amdgcn_wave_barrier();            // pin LDS write->read order

        // ---- O += P V (A from Ps, B from transposed Vs) ----
        const short8 pa0 = *(const short8*)&Ps[wave][l16 * PK + quad * 8];
        const short8 pa1 = *(const short8*)&Ps[wave][l16 * PK + 32 + quad * 8];
#pragma unroll
        for (int nf = 0; nf < 4; ++nf) {
            const int d   = nf * 16 + l16;
            const int swz = ((d >> 3) & 7) << 3;
            const short8 bv0 = *(const short8*)&Vs[d * PK + ((quad * 8) ^ swz)];
            const short8 bv1 = *(const short8*)&Vs[d * PK + ((32 + quad * 8) ^ swz)];
            o[nf] = __builtin_amdgcn_mfma_f32_16x16x32_bf16(pa0, bv0, o[nf], 0, 0, 0);
            o[nf] = __builtin_amdgcn_mfma_f32_16x16x32_bf16(pa1, bv1, o[nf], 0, 0, 0);
        }
    }

    // ---- finalize: reduce srow across the 16-lane group, write O ----
#pragma unroll
    for (int r = 0; r < 4; ++r) {
        float s = srow[r];
        s += __shfl_xor(s, 1);
        s += __shfl_xor(s, 2);
        s += __shfl_xor(s, 4);
        s += __shfl_xor(s, 8);
        srow[r] = 1.f / s;
    }
#pragma unroll
    for (int nf = 0; nf < 4; ++nf)
#pragma unroll
        for (int r = 0; r < 4; ++r) {
            const size_t addr = base + (size_t)(q0 + wave * 16 + quad * 4 + r) * Dv
                              + nf * 16 + l16;
            Op[addr] = f2bf(o[nf][r] * srow[r]);
        }
}

// ---------------------------------------------------------------------------
extern "C" void kernel_launch(void* const* d_in, const int* in_sizes, int n_in,
                              void* d_out, int out_size, void* d_ws, size_t ws_size,
                              hipStream_t stream)
{
    const int*   x    = (const int*)  d_in[0];
    const float* ctx  = (const float*)d_in[1];
    const float* emb  = (const float*)d_in[2];
    const float* wq_s = (const float*)d_in[3];
    const float* wk_s = (const float*)d_in[4];
    const float* wv_s = (const float*)d_in[5];
    const float* wo_s = (const float*)d_in[6];
    const float* wq_c = (const float*)d_in[7];
    const float* wk_c = (const float*)d_in[8];
    const float* wv_c = (const float*)d_in[9];
    const float* wo_c = (const float*)d_in[10];
    const float* w1   = (const float*)d_in[11];
    const float* b1   = (const float*)d_in[12];
    const float* w2   = (const float*)d_in[13];
    const float* b2   = (const float*)d_in[14];
    const float* ln1g = (const float*)d_in[15];
    const float* ln1b = (const float*)d_in[16];
    const float* ln2g = (const float*)d_in[17];
    const float* ln2b = (const float*)d_in[18];
    const float* ln3g = (const float*)d_in[19];
    const float* ln3b = (const float*)d_in[20];
    const float* lnfg = (const float*)d_in[21];
    const float* lnfb = (const float*)d_in[22];
    float* out = (float*)d_out;

    // workspace layout (22 MB):
    // [0,4M)   h fp32
    // [4,6M)   y bf16
    // [6,8M)   ao bf16
    // [8,10M)  ctx bf16
    // [10,12M) qb bf16          -- aliased by ff bf16 [10,18M)
    // [18,20M) kb bf16
    // [20,22M) vb bf16
    char* wsb = (char*)d_ws;
    float* h      = (float*)(wsb);
    short* y_bf   = (short*)(wsb + (4u  << 20));
    short* ao_bf  = (short*)(wsb + (6u  << 20));
    short* ctx_bf = (short*)(wsb + (8u  << 20));
    short* qb     = (short*)(wsb + (10u << 20));
    short* ff_bf  = (short*)(wsb + (10u << 20));
    short* kb     = (short*)(wsb + (18u << 20));
    short* vb     = (short*)(wsb + (20u << 20));

    const dim3 blk(256);
    const dim3 gAttn(Lv / 64, Hv, Bv);      // 16 x 8 x 2 = 256 blocks
    const dim3 gD(Dv / 64, Mv / 128);       // BN=64  : (8,16)
    const dim3 gF(Fv / 128, Mv / 128);      // BN=128 : (16,16)
    const dim3 gV(Vv / 128, Mv / 128);      // BN=128 : (250,16)

    embed_kernel<<<Mv, blk, 0, stream>>>(x, emb, h);
    cvt_kernel<<<(Mv * Dv) / 1024, blk, 0, stream>>>(ctx, ctx_bf);

    for (int i = 0; i < NBv; ++i) {
        const size_t wOff = (size_t)i * Dv * Dv;
        // --- self attention ---
        ln_kernel<<<Mv, blk, 0, stream>>>(h, ln1g + i * Dv, ln1b + i * Dv, y_bf);
        mgemm<64, false, true><<<gD, blk, 0, stream>>>(y_bf, wq_s + wOff, qb, Mv, Dv, Dv, nullptr, nullptr, 0);
        mgemm<64, false, true><<<gD, blk, 0, stream>>>(y_bf, wk_s + wOff, kb, Mv, Dv, Dv, nullptr, nullptr, 0);
        mgemm<64, false, true><<<gD, blk, 0, stream>>>(y_bf, wv_s + wOff, vb, Mv, Dv, Dv, nullptr, nullptr, 0);
        attn_mfma<<<gAttn, blk, 0, stream>>>(qb, kb, vb, ao_bf, 1);
        mgemm<64, false, false><<<gD, blk, 0, stream>>>(ao_bf, wo_s + wOff, h, Mv, Dv, Dv, nullptr, h, 0);
        // --- cross attention ---
        ln_kernel<<<Mv, blk, 0, stream>>>(h, ln2g + i * Dv, ln2b + i * Dv, y_bf);
        mgemm<64, false, true><<<gD, blk, 0, stream>>>(y_bf,   wq_c + wOff, qb, Mv, Dv, Dv, nullptr, nullptr, 0);
        mgemm<64, false, true><<<gD, blk, 0, stream>>>(ctx_bf, wk_c + wOff, kb, Mv, Dv, Dv, nullptr, nullptr, 0);
        mgemm<64, false, true><<<gD, blk, 0, stream>>>(ctx_bf, wv_c + wOff, vb, Mv, Dv, Dv, nullptr, nullptr, 0);
        attn_mfma<<<gAttn, blk, 0, stream>>>(qb, kb, vb, ao_bf, 0);
        mgemm<64, false, false><<<gD, blk, 0, stream>>>(ao_bf, wo_c + wOff, h, Mv, Dv, Dv, nullptr, h, 0);
        // --- feed forward ---
        ln_kernel<<<Mv, blk, 0, stream>>>(h, ln3g + i * Dv, ln3b + i * Dv, y_bf);
        mgemm<128, false, true><<<gF, blk, 0, stream>>>(y_bf, w1 + (size_t)i * Dv * Fv, ff_bf,
                                                        Mv, Fv, Dv, b1 + (size_t)i * Fv, nullptr, 1);
        mgemm<64, false, false><<<gD, blk, 0, stream>>>(ff_bf, w2 + (size_t)i * Fv * Dv, h,
                                                        Mv, Dv, Fv, b2 + (size_t)i * Dv, h, 0);
    }

    ln_kernel<<<Mv, blk, 0, stream>>>(h, lnfg, lnfb, y_bf);
    mgemm<128, true, false><<<gV, blk, 0, stream>>>(y_bf, emb, out, Mv, Vv, Dv, nullptr, nullptr, 0);
}

// Round 2
// 2606.589 us; speedup vs baseline: 2.0100x; 1.0460x over previous
//
#include <hip/hip_runtime.h>
#include <math.h>

// Problem constants
#define Bv 2
#define Lv 1024
#define Dv 512
#define Hv 8
#define DH 64
#define Fv 2048
#define NBv 6
#define Vv 32000
#define Mv (Bv*Lv)          // 2048 rows
#define QS 1536             // fused qkv row stride (q|k|v concat)
#define NEGINF -1e10f

typedef __attribute__((ext_vector_type(8))) short short8;   // 8 bf16
typedef __attribute__((ext_vector_type(4))) short short4v;  // 4 bf16
typedef __attribute__((ext_vector_type(4))) float floatx4;
typedef __attribute__((address_space(1))) const void gvoid;
typedef __attribute__((address_space(3))) void svoid;

__device__ __forceinline__ short f2bf(float f) {
    union { float f; unsigned u; } v; v.f = f;
    unsigned r = v.u + 0x7fffu + ((v.u >> 16) & 1u);   // RNE
    return (short)(r >> 16);
}

// ---------------------------------------------------------------------------
// Embedding + sinusoidal positional encoding (fp32 h)
__global__ __launch_bounds__(256)
void embed_kernel(const int* __restrict__ xi, const float* __restrict__ emb,
                  float* __restrict__ h)
{
    const int row = blockIdx.x;
    const int l   = row & (Lv - 1);
    const int tok = xi[row];
    const int tid = threadIdx.x;
#pragma unroll
    for (int s = 0; s < 2; ++s) {
        const int d  = tid + s * 256;
        const int dd = d & 255;
        const float freq = powf(10000.f, (float)dd * (1.f / 256.f));
        const float arg  = (float)l / freq;
        const float pe   = (d < 256) ? sinf(arg) : cosf(arg);
        h[(size_t)row * Dv + d] = emb[(size_t)tok * Dv + d] * 22.62741699796952f + pe;
    }
}

// ---------------------------------------------------------------------------
// fp32 -> bf16 convert
__global__ __launch_bounds__(256)
void cvt_kernel(const float* __restrict__ X, short* __restrict__ Y)
{
    const int i = (blockIdx.x * 256 + threadIdx.x) * 4;
    const float4 v = *(const float4*)(X + i);
    short4v p; p.x = f2bf(v.x); p.y = f2bf(v.y); p.z = f2bf(v.z); p.w = f2bf(v.w);
    *(short4v*)(Y + i) = p;
}

// ---------------------------------------------------------------------------
// LayerNorm: one block per row, 256 threads, D=512; bf16 output
__global__ __launch_bounds__(256)
void ln_kernel(const float* __restrict__ X, const float* __restrict__ g,
               const float* __restrict__ bta, short* __restrict__ Y)
{
    const int row = blockIdx.x, tid = threadIdx.x;
    const float* xr = X + (size_t)row * Dv;
    const float x0 = xr[tid], x1 = xr[tid + 256];
    __shared__ float red[4];

    float s = x0 + x1;
#pragma unroll
    for (int off = 32; off; off >>= 1) s += __shfl_xor(s, off);
    if ((tid & 63) == 0) red[tid >> 6] = s;
    __syncthreads();
    const float mean = (red[0] + red[1] + red[2] + red[3]) * (1.f / Dv);
    __syncthreads();

    const float d0 = x0 - mean, d1 = x1 - mean;
    float v = d0 * d0 + d1 * d1;
#pragma unroll
    for (int off = 32; off; off >>= 1) v += __shfl_xor(v, off);
    if ((tid & 63) == 0) red[tid >> 6] = v;
    __syncthreads();
    const float var  = (red[0] + red[1] + red[2] + red[3]) * (1.f / Dv);
    const float rstd = rsqrtf(var + 1e-6f);

    Y[(size_t)row * Dv + tid]       = f2bf(d0 * rstd * g[tid]       + bta[tid]);
    Y[(size_t)row * Dv + tid + 256] = f2bf(d1 * rstd * g[tid + 256] + bta[tid + 256]);
}

// ---------------------------------------------------------------------------
// bf16 MFMA GEMM.
// A: bf16 [M,K] rm (global_load_lds staging).
// BMODE 0: B fp32 [K,N] rm (VALU convert during staging)
// BMODE 1: B fp32 [N,K] rm (VALU convert)
// BMODE 2: B bf16 [N,K] rm (global_load_lds staging, no convert)
// C = A@B (+bias) (+residual fp32) (relu?).
// Block 256 = 4 waves (2x2); wave tile (BM/2) x (BN/2).
// SWZ: 1-D grid with bijective XCD-chunked mapping, m-fastest (vocab only:
//      BM=BN=128, M=2048, N=32000 -> 16 x 250 blocks, chunk=500).
template <int BM, int BN, int BMODE, bool OUTBF, bool SWZ>
__global__ __launch_bounds__(256)
void mgemm(const short* __restrict__ A, const float* __restrict__ B,
           void* __restrict__ Cp, int M, int N, int K,
           const float* __restrict__ bias,
           const float* __restrict__ residual, int relu)
{
    constexpr int BK = 32;
    constexpr int WMT = BM / 2, MI = WMT / 16, NF = BN / 32;
    __shared__ short As[BM * BK];
    __shared__ short Bs[BN * BK];
    const int tid  = threadIdx.x;
    const int wave = tid >> 6, lane = tid & 63;
    const int wm = wave & 1, wn = wave >> 1;
    const int quad = lane >> 4, l16 = lane & 15;

    int m0, n0;
    if (SWZ) {
        const int wg = (blockIdx.x & 7) * 500 + (blockIdx.x >> 3);  // bijective, 4000 wgs
        m0 = (wg & 15) * BM;
        n0 = (wg >> 4) * BN;
    } else {
        m0 = blockIdx.y * BM;
        n0 = blockIdx.x * BN;
    }

    floatx4 acc[MI][NF];
#pragma unroll
    for (int i = 0; i < MI; ++i)
#pragma unroll
        for (int j = 0; j < NF; ++j)
            acc[i][j] = (floatx4){0.f, 0.f, 0.f, 0.f};

    for (int k0 = 0; k0 < K; k0 += BK) {
        __syncthreads();
        // ---- A staging: 16B chunks via global_load_lds ----
#pragma unroll
        for (int s = 0; s < BM / 64; ++s) {
            const int c = s * 256 + tid;             // chunk = 16B = 8 bf16
            const int row = c >> 2, kp = (c & 3) << 3;
            const short* gp = A + (size_t)(m0 + row) * K + k0 + kp;
            __builtin_amdgcn_global_load_lds((gvoid*)gp, (svoid*)((char*)As + c * 16),
                                             16, 0, 0);
        }
        // ---- B staging ----
        if (BMODE == 0) {
            constexpr int QN = BN / 4;               // n-quads
            const int qn = tid % QN, kq = tid / QN;
            if (kq < 8) {
                const float* gp = B + (size_t)(k0 + kq * 4) * N + n0 + qn * 4;
                const float4 r0 = *(const float4*)(gp);
                const float4 r1 = *(const float4*)(gp + N);
                const float4 r2 = *(const float4*)(gp + 2 * (size_t)N);
                const float4 r3 = *(const float4*)(gp + 3 * (size_t)N);
                short4v p;
                p.x = f2bf(r0.x); p.y = f2bf(r1.x); p.z = f2bf(r2.x); p.w = f2bf(r3.x);
                *(short4v*)&Bs[(qn * 4 + 0) * BK + kq * 4] = p;
                p.x = f2bf(r0.y); p.y = f2bf(r1.y); p.z = f2bf(r2.y); p.w = f2bf(r3.y);
                *(short4v*)&Bs[(qn * 4 + 1) * BK + kq * 4] = p;
                p.x = f2bf(r0.z); p.y = f2bf(r1.z); p.z = f2bf(r2.z); p.w = f2bf(r3.z);
                *(short4v*)&Bs[(qn * 4 + 2) * BK + kq * 4] = p;
                p.x = f2bf(r0.w); p.y = f2bf(r1.w); p.z = f2bf(r2.w); p.w = f2bf(r3.w);
                *(short4v*)&Bs[(qn * 4 + 3) * BK + kq * 4] = p;
            }
        } else if (BMODE == 1) {
#pragma unroll
            for (int f = 0; f < BN / 32; ++f) {
                const int gidx = f * 256 + tid;      // float4 index
                const int n = gidx >> 3, q = gidx & 7;
                const float4 r = *(const float4*)(B + (size_t)(n0 + n) * K + k0 + q * 4);
                short4v p; p.x = f2bf(r.x); p.y = f2bf(r.y); p.z = f2bf(r.z); p.w = f2bf(r.w);
                *(short4v*)&Bs[n * BK + q * 4] = p;
            }
        } else {
            const short* Bb = (const short*)B;       // bf16 [N,K]
#pragma unroll
            for (int s = 0; s < BN / 64; ++s) {
                const int c = s * 256 + tid;
                const int row = c >> 2, kp = (c & 3) << 3;
                const short* gp = Bb + (size_t)(n0 + row) * K + k0 + kp;
                __builtin_amdgcn_global_load_lds((gvoid*)gp, (svoid*)((char*)Bs + c * 16),
                                                 16, 0, 0);
            }
        }
        __syncthreads();
        // ---- compute ----
        short8 af[MI];
#pragma unroll
        for (int mi = 0; mi < MI; ++mi)
            af[mi] = *(short8*)&As[(wm * WMT + mi * 16 + l16) * BK + quad * 8];
#pragma unroll
        for (int ni = 0; ni < NF; ++ni) {
            const short8 bfr = *(short8*)&Bs[(wn * (BN / 2) + ni * 16 + l16) * BK + quad * 8];
#pragma unroll
            for (int mi = 0; mi < MI; ++mi)
                acc[mi][ni] = __builtin_amdgcn_mfma_f32_16x16x32_bf16(af[mi], bfr, acc[mi][ni], 0, 0, 0);
        }
    }

    // ---- epilogue ----
#pragma unroll
    for (int mi = 0; mi < MI; ++mi)
#pragma unroll
        for (int ni = 0; ni < NF; ++ni)
#pragma unroll
            for (int r = 0; r < 4; ++r) {
                const int m = m0 + wm * WMT + mi * 16 + quad * 4 + r;
                const int n = n0 + wn * (BN / 2) + ni * 16 + l16;
                float v = acc[mi][ni][r];
                if (bias)     v += bias[n];
                if (residual) v += residual[(size_t)m * N + n];
                if (relu)     v = fmaxf(v, 0.f);
                if (OUTBF) ((short*)Cp)[(size_t)m * N + n] = f2bf(v);
                else       ((float*)Cp)[(size_t)m * N + n] = v;
            }
}

// ---------------------------------------------------------------------------
// Fused QKV GEMM: computes [y@wq | a@wk | a@wv] into qkv [Mv][1536] bf16.
// Per block: weight/A-operand selected by n0 (each BN=64 block within one
// 512-col section).  BM=64 -> grid (24, 32) = 768 blocks.
template <int BM>
__global__ __launch_bounds__(256)
void qkv_gemm(const short* __restrict__ Aq, const short* __restrict__ Akv,
              const float* __restrict__ B0, const float* __restrict__ B1,
              const float* __restrict__ B2, short* __restrict__ QKV)
{
    constexpr int BN = 64, BK = 32, N = Dv, K = Dv;
    constexpr int WMT = BM / 2, MI = WMT / 16, NF = 2;
    __shared__ short As[BM * BK];
    __shared__ short Bs[BN * BK];
    const int tid  = threadIdx.x;
    const int wave = tid >> 6, lane = tid & 63;
    const int wm = wave & 1, wn = wave >> 1;
    const int quad = lane >> 4, l16 = lane & 15;
    const int n0g = blockIdx.x * BN, m0 = blockIdx.y * BM;
    const int wsel = n0g >> 9, n0 = n0g & 511;
    const short* A = (wsel == 0) ? Aq : Akv;
    const float* B = (wsel == 0) ? B0 : (wsel == 1) ? B1 : B2;

    floatx4 acc[MI][NF];
#pragma unroll
    for (int i = 0; i < MI; ++i)
#pragma unroll
        for (int j = 0; j < NF; ++j)
            acc[i][j] = (floatx4){0.f, 0.f, 0.f, 0.f};

    for (int k0 = 0; k0 < K; k0 += BK) {
        __syncthreads();
#pragma unroll
        for (int s = 0; s < BM / 64; ++s) {
            const int c = s * 256 + tid;
            const int row = c >> 2, kp = (c & 3) << 3;
            const short* gp = A + (size_t)(m0 + row) * K + k0 + kp;
            __builtin_amdgcn_global_load_lds((gvoid*)gp, (svoid*)((char*)As + c * 16),
                                             16, 0, 0);
        }
        {
            const int qn = tid & 15, kq = tid >> 4;
            if (kq < 8) {
                const float* gp = B + (size_t)(k0 + kq * 4) * N + n0 + qn * 4;
                const float4 r0 = *(const float4*)(gp);
                const float4 r1 = *(const float4*)(gp + N);
                const float4 r2 = *(const float4*)(gp + 2 * (size_t)N);
                const float4 r3 = *(const float4*)(gp + 3 * (size_t)N);
                short4v p;
                p.x = f2bf(r0.x); p.y = f2bf(r1.x); p.z = f2bf(r2.x); p.w = f2bf(r3.x);
                *(short4v*)&Bs[(qn * 4 + 0) * BK + kq * 4] = p;
                p.x = f2bf(r0.y); p.y = f2bf(r1.y); p.z = f2bf(r2.y); p.w = f2bf(r3.y);
                *(short4v*)&Bs[(qn * 4 + 1) * BK + kq * 4] = p;
                p.x = f2bf(r0.z); p.y = f2bf(r1.z); p.z = f2bf(r2.z); p.w = f2bf(r3.z);
                *(short4v*)&Bs[(qn * 4 + 2) * BK + kq * 4] = p;
                p.x = f2bf(r0.w); p.y = f2bf(r1.w); p.z = f2bf(r2.w); p.w = f2bf(r3.w);
                *(short4v*)&Bs[(qn * 4 + 3) * BK + kq * 4] = p;
            }
        }
        __syncthreads();
        short8 af[MI];
#pragma unroll
        for (int mi = 0; mi < MI; ++mi)
            af[mi] = *(short8*)&As[(wm * WMT + mi * 16 + l16) * BK + quad * 8];
#pragma unroll
        for (int ni = 0; ni < NF; ++ni) {
            const short8 bfr = *(short8*)&Bs[(wn * 32 + ni * 16 + l16) * BK + quad * 8];
#pragma unroll
            for (int mi = 0; mi < MI; ++mi)
                acc[mi][ni] = __builtin_amdgcn_mfma_f32_16x16x32_bf16(af[mi], bfr, acc[mi][ni], 0, 0, 0);
        }
    }

#pragma unroll
    for (int mi = 0; mi < MI; ++mi)
#pragma unroll
        for (int ni = 0; ni < NF; ++ni)
#pragma unroll
            for (int r = 0; r < 4; ++r) {
                const int m = m0 + wm * WMT + mi * 16 + quad * 4 + r;
                const int n = n0g + wn * 32 + ni * 16 + l16;
                QKV[(size_t)m * QS + n] = f2bf(acc[mi][ni][r]);
            }
}

// ---------------------------------------------------------------------------
// Flash attention, bf16 MFMA path.  O = softmax(Q K^T / 8 (+causal)) V.
// QKV: bf16 [B*L, 1536] (q|k|v), head offset h*64.  O: bf16 [B*L, 512].
// grid (L/64, H, B); block 256 = 4 waves; each wave owns 16 query rows.
__global__ __launch_bounds__(256)
void attn_mfma(const short* __restrict__ QKV, short* __restrict__ Op, int causal)
{
    constexpr int PK = 72;                 // row pad: 144 B -> <=2-way conflicts
    __shared__ short Ks[64 * PK];
    __shared__ short Vs[64 * PK];          // transposed: Vs[d][j^swz]
    __shared__ short Ps[4][16 * PK];       // per-wave P re-fragment buffer
    const int tid  = threadIdx.x;
    const int wave = tid >> 6, lane = tid & 63;
    const int quad = lane >> 4, l16 = lane & 15;
    const int hh = blockIdx.y, bb = blockIdx.z;
    const int q0 = blockIdx.x * 64;
    const size_t base  = (size_t)bb * Lv * QS + (size_t)hh * DH;
    const short* Qp = QKV + base;
    const short* Kp = QKV + base + 512;
    const short* Vp = QKV + base + 1024;
    const size_t obase = (size_t)bb * Lv * Dv + (size_t)hh * DH;

    short8 aq[2];
    {
        const short* qp = Qp + (size_t)(q0 + wave * 16 + l16) * QS + quad * 8;
        aq[0] = *(const short8*)qp;
        aq[1] = *(const short8*)(qp + 32);
    }

    floatx4 o[4];
#pragma unroll
    for (int i = 0; i < 4; ++i) o[i] = (floatx4){0.f, 0.f, 0.f, 0.f};
    float mrow[4] = {-3.4e38f, -3.4e38f, -3.4e38f, -3.4e38f};
    float srow[4] = {0.f, 0.f, 0.f, 0.f};

    const int ntiles = causal ? (q0 / 64 + 1) : (Lv / 64);

    for (int t = 0; t < ntiles; ++t) {
        const int j0 = t * 64;
        __syncthreads();
#pragma unroll
        for (int s = 0; s < 2; ++s) {
            const int c = s * 256 + tid;
            const int j = c >> 3, off = (c & 7) * 8;
            const size_t grow = (size_t)(j0 + j) * QS + off;
            *(short8*)&Ks[j * PK + off] = *(const short8*)(Kp + grow);
            const short8 v = *(const short8*)(Vp + grow);
            const int jx = j ^ ((c & 7) << 3);     // swz = ((d>>3)&7)<<3, d=off+e
#pragma unroll
            for (int e = 0; e < 8; ++e)
                Vs[(off + e) * PK + jx] = v[e];
        }
        __syncthreads();

        // ---- S = Q K^T (4 col-frags of 16) ----
        floatx4 sf[4];
#pragma unroll
        for (int nf = 0; nf < 4; ++nf) {
            const short8 bk0 = *(const short8*)&Ks[(nf * 16 + l16) * PK + quad * 8];
            const short8 bk1 = *(const short8*)&Ks[(nf * 16 + l16) * PK + 32 + quad * 8];
            floatx4 z = (floatx4){0.f, 0.f, 0.f, 0.f};
            z = __builtin_amdgcn_mfma_f32_16x16x32_bf16(aq[0], bk0, z, 0, 0, 0);
            z = __builtin_amdgcn_mfma_f32_16x16x32_bf16(aq[1], bk1, z, 0, 0, 0);
            sf[nf] = z;
        }

        const bool mask = causal && (j0 == q0);
#pragma unroll
        for (int nf = 0; nf < 4; ++nf) {
            const int jabs = j0 + nf * 16 + l16;
#pragma unroll
            for (int r = 0; r < 4; ++r) {
                float v = sf[nf][r] * 0.125f;
                if (mask && jabs > q0 + wave * 16 + quad * 4 + r) v = NEGINF;
                sf[nf][r] = v;
            }
        }

        // ---- online softmax update ----
#pragma unroll
        for (int r = 0; r < 4; ++r) {
            float v = fmaxf(fmaxf(sf[0][r], sf[1][r]), fmaxf(sf[2][r], sf[3][r]));
            v = fmaxf(v, __shfl_xor(v, 1));
            v = fmaxf(v, __shfl_xor(v, 2));
            v = fmaxf(v, __shfl_xor(v, 4));
            v = fmaxf(v, __shfl_xor(v, 8));
            const float mnew = fmaxf(mrow[r], v);
            const float corr = __expf(mrow[r] - mnew);
            mrow[r] = mnew;
            srow[r] *= corr;
#pragma unroll
            for (int nf = 0; nf < 4; ++nf) o[nf][r] *= corr;
        }

        // ---- P = exp(S - m) -> bf16 via per-wave LDS re-fragment ----
#pragma unroll
        for (int nf = 0; nf < 4; ++nf) {
#pragma unroll
            for (int r = 0; r < 4; ++r) {
                const float pv = __expf(sf[nf][r] - mrow[r]);
                srow[r] += pv;
                Ps[wave][(quad * 4 + r) * PK + nf * 16 + l16] = f2bf(pv);
            }
        }
        __builtin_amdgcn_wave_barrier();

        // ---- O += P V ----
        const short8 pa0 = *(const short8*)&Ps[wave][l16 * PK + quad * 8];
        const short8 pa1 = *(const short8*)&Ps[wave][l16 * PK + 32 + quad * 8];
#pragma unroll
        for (int nf = 0; nf < 4; ++nf) {
            const int d   = nf * 16 + l16;
            const int swz = ((d >> 3) & 7) << 3;
            const short8 bv0 = *(const short8*)&Vs[d * PK + ((quad * 8) ^ swz)];
            const short8 bv1 = *(const short8*)&Vs[d * PK + ((32 + quad * 8) ^ swz)];
            o[nf] = __builtin_amdgcn_mfma_f32_16x16x32_bf16(pa0, bv0, o[nf], 0, 0, 0);
            o[nf] = __builtin_amdgcn_mfma_f32_16x16x32_bf16(pa1, bv1, o[nf], 0, 0, 0);
        }
    }

#pragma unroll
    for (int r = 0; r < 4; ++r) {
        float s = srow[r];
        s += __shfl_xor(s, 1);
        s += __shfl_xor(s, 2);
        s += __shfl_xor(s, 4);
        s += __shfl_xor(s, 8);
        srow[r] = 1.f / s;
    }
#pragma unroll
    for (int nf = 0; nf < 4; ++nf)
#pragma unroll
        for (int r = 0; r < 4; ++r) {
            const size_t addr = obase + (size_t)(q0 + wave * 16 + quad * 4 + r) * Dv
                              + nf * 16 + l16;
            Op[addr] = f2bf(o[nf][r] * srow[r]);
        }
}

// ---------------------------------------------------------------------------
extern "C" void kernel_launch(void* const* d_in, const int* in_sizes, int n_in,
                              void* d_out, int out_size, void* d_ws, size_t ws_size,
                              hipStream_t stream)
{
    const int*   x    = (const int*)  d_in[0];
    const float* ctx  = (const float*)d_in[1];
    const float* emb  = (const float*)d_in[2];
    const float* wq_s = (const float*)d_in[3];
    const float* wk_s = (const float*)d_in[4];
    const float* wv_s = (const float*)d_in[5];
    const float* wo_s = (const float*)d_in[6];
    const float* wq_c = (const float*)d_in[7];
    const float* wk_c = (const float*)d_in[8];
    const float* wv_c = (const float*)d_in[9];
    const float* wo_c = (const float*)d_in[10];
    const float* w1   = (const float*)d_in[11];
    const float* b1   = (const float*)d_in[12];
    const float* w2   = (const float*)d_in[13];
    const float* b2   = (const float*)d_in[14];
    const float* ln1g = (const float*)d_in[15];
    const float* ln1b = (const float*)d_in[16];
    const float* ln2g = (const float*)d_in[17];
    const float* ln2b = (const float*)d_in[18];
    const float* ln3g = (const float*)d_in[19];
    const float* ln3b = (const float*)d_in[20];
    const float* lnfg = (const float*)d_in[21];
    const float* lnfb = (const float*)d_in[22];
    float* out = (float*)d_out;

    // workspace layout:
    // [0,4M)    h fp32
    // [4,6M)    y bf16
    // [6,8M)    ao bf16
    // [8,10M)   ctx bf16
    // [10,16M)  qkv bf16 [2048][1536]   -- aliased by ff bf16 [10,18M)
    // [18,~50M) emb bf16 (optional, if workspace allows)
    char* wsb = (char*)d_ws;
    float* h      = (float*)(wsb);
    short* y_bf   = (short*)(wsb + (4u  << 20));
    short* ao_bf  = (short*)(wsb + (6u  << 20));
    short* ctx_bf = (short*)(wsb + (8u  << 20));
    short* qkv    = (short*)(wsb + (10u << 20));
    short* ff_bf  = (short*)(wsb + (10u << 20));
    short* emb_bf = (short*)(wsb + (18u << 20));
    const bool fastv = ws_size >= (52u << 20);

    const dim3 blk(256);
    const dim3 gAttn(Lv / 64, Hv, Bv);          // 256 blocks
    const dim3 gQKV(QS / 64, Mv / 64);          // (24,32) = 768 blocks
    const dim3 gD(Dv / 64, Mv / 64);            // (8,32)  = 256 blocks
    const dim3 gF(Fv / 128, Mv / 64);           // (16,32) = 512 blocks
    const dim3 gV(16 * 250);                    // 4000 blocks, swizzled 1-D

    embed_kernel<<<Mv, blk, 0, stream>>>(x, emb, h);
    cvt_kernel<<<(Mv * Dv) / 1024, blk, 0, stream>>>(ctx, ctx_bf);
    if (fastv)
        cvt_kernel<<<(Vv * Dv) / 1024, blk, 0, stream>>>(emb, emb_bf);

    for (int i = 0; i < NBv; ++i) {
        const size_t wOff = (size_t)i * Dv * Dv;
        // --- self attention ---
        ln_kernel<<<Mv, blk, 0, stream>>>(h, ln1g + i * Dv, ln1b + i * Dv, y_bf);
        qkv_gemm<64><<<gQKV, blk, 0, stream>>>(y_bf, y_bf,
                                               wq_s + wOff, wk_s + wOff, wv_s + wOff, qkv);
        attn_mfma<<<gAttn, blk, 0, stream>>>(qkv, ao_bf, 1);
        mgemm<64, 64, 0, false, false><<<gD, blk, 0, stream>>>(ao_bf, wo_s + wOff, h,
                                                               Mv, Dv, Dv, nullptr, h, 0);
        // --- cross attention ---
        ln_kernel<<<Mv, blk, 0, stream>>>(h, ln2g + i * Dv, ln2b + i * Dv, y_bf);
        qkv_gemm<64><<<gQKV, blk, 0, stream>>>(y_bf, ctx_bf,
                                               wq_c + wOff, wk_c + wOff, wv_c + wOff, qkv);
        attn_mfma<<<gAttn, blk, 0, stream>>>(qkv, ao_bf, 0);
        mgemm<64, 64, 0, false, false><<<gD, blk, 0, stream>>>(ao_bf, wo_c + wOff, h,
                                                               Mv, Dv, Dv, nullptr, h, 0);
        // --- feed forward ---
        ln_kernel<<<Mv, blk, 0, stream>>>(h, ln3g + i * Dv, ln3b + i * Dv, y_bf);
        mgemm<64, 128, 0, true, false><<<gF, blk, 0, stream>>>(y_bf, w1 + (size_t)i * Dv * Fv,
                                                               ff_bf, Mv, Fv, Dv,
                                                               b1 + (size_t)i * Fv, nullptr, 1);
        mgemm<64, 64, 0, false, false><<<gD, blk, 0, stream>>>(ff_bf, w2 + (size_t)i * Fv * Dv,
                                                               h, Mv, Dv, Fv,
                                                               b2 + (size_t)i * Dv, h, 0);
    }

    ln_kernel<<<Mv, blk, 0, stream>>>(h, lnfg, lnfb, y_bf);
    if (fastv)
        mgemm<128, 128, 2, false, true><<<gV, blk, 0, stream>>>(y_bf, (const float*)emb_bf,
                                                                out, Mv, Vv, Dv,
                                                                nullptr, nullptr, 0);
    else
        mgemm<128, 128, 1, false, true><<<gV, blk, 0, stream>>>(y_bf, emb, out,
                                                                Mv, Vv, Dv,
                                                                nullptr, nullptr, 0);
}

// Round 3
// 1670.926 us; speedup vs baseline: 3.1355x; 1.5600x over previous
//
#include <hip/hip_runtime.h>
#include <math.h>

// Problem constants
#define Bv 2
#define Lv 1024
#define Dv 512
#define Hv 8
#define DH 64
#define Fv 2048
#define NBv 6
#define Vv 32000
#define Mv (Bv*Lv)          // 2048 rows
#define QS 1536             // fused qkv row stride (q|k|v concat)
#define NEGINF -1e10f

typedef __attribute__((ext_vector_type(8))) short short8;   // 8 bf16
typedef __attribute__((ext_vector_type(4))) short short4v;  // 4 bf16
typedef __attribute__((ext_vector_type(4))) float floatx4;
typedef __attribute__((address_space(1))) const void gvoid;
typedef __attribute__((address_space(3))) void svoid;

__device__ __forceinline__ short f2bf(float f) {
    union { float f; unsigned u; } v; v.f = f;
    unsigned r = v.u + 0x7fffu + ((v.u >> 16) & 1u);   // RNE
    return (short)(r >> 16);
}

// ---------------------------------------------------------------------------
// Embedding + sinusoidal positional encoding (fp32 h)
__global__ __launch_bounds__(256)
void embed_kernel(const int* __restrict__ xi, const float* __restrict__ emb,
                  float* __restrict__ h)
{
    const int row = blockIdx.x;
    const int l   = row & (Lv - 1);
    const int tok = xi[row];
    const int tid = threadIdx.x;
#pragma unroll
    for (int s = 0; s < 2; ++s) {
        const int d  = tid + s * 256;
        const int dd = d & 255;
        const float freq = powf(10000.f, (float)dd * (1.f / 256.f));
        const float arg  = (float)l / freq;
        const float pe   = (d < 256) ? sinf(arg) : cosf(arg);
        h[(size_t)row * Dv + d] = emb[(size_t)tok * Dv + d] * 22.62741699796952f + pe;
    }
}

// ---------------------------------------------------------------------------
// fp32 -> bf16 convert
__global__ __launch_bounds__(256)
void cvt_kernel(const float* __restrict__ X, short* __restrict__ Y)
{
    const int i = (blockIdx.x * 256 + threadIdx.x) * 4;
    const float4 v = *(const float4*)(X + i);
    short4v p; p.x = f2bf(v.x); p.y = f2bf(v.y); p.z = f2bf(v.z); p.w = f2bf(v.w);
    *(short4v*)(Y + i) = p;
}

// ---------------------------------------------------------------------------
// LayerNorm: one block per row, 256 threads, D=512; bf16 output
__global__ __launch_bounds__(256)
void ln_kernel(const float* __restrict__ X, const float* __restrict__ g,
               const float* __restrict__ bta, short* __restrict__ Y)
{
    const int row = blockIdx.x, tid = threadIdx.x;
    const float* xr = X + (size_t)row * Dv;
    const float x0 = xr[tid], x1 = xr[tid + 256];
    __shared__ float red[4];

    float s = x0 + x1;
#pragma unroll
    for (int off = 32; off; off >>= 1) s += __shfl_xor(s, off);
    if ((tid & 63) == 0) red[tid >> 6] = s;
    __syncthreads();
    const float mean = (red[0] + red[1] + red[2] + red[3]) * (1.f / Dv);
    __syncthreads();

    const float d0 = x0 - mean, d1 = x1 - mean;
    float v = d0 * d0 + d1 * d1;
#pragma unroll
    for (int off = 32; off; off >>= 1) v += __shfl_xor(v, off);
    if ((tid & 63) == 0) red[tid >> 6] = v;
    __syncthreads();
    const float var  = (red[0] + red[1] + red[2] + red[3]) * (1.f / Dv);
    const float rstd = rsqrtf(var + 1e-6f);

    Y[(size_t)row * Dv + tid]       = f2bf(d0 * rstd * g[tid]       + bta[tid]);
    Y[(size_t)row * Dv + tid + 256] = f2bf(d1 * rstd * g[tid + 256] + bta[tid + 256]);
}

// ---------------------------------------------------------------------------
// bf16 MFMA GEMM, BK=64, XOR-swizzled LDS (col8 ^ ((row&7)<<3) in shorts).
// A: bf16 [M,K] rm via global_load_lds with pre-swizzled source.
// BMODE 0: B fp32 [K,N] rm (VALU convert, swizzled stores)
// BMODE 1: B fp32 [N,K] rm (VALU convert, swizzled stores)
// BMODE 2: B bf16 [N,K] rm (global_load_lds, pre-swizzled source)
// C = A@B (+bias) (+residual fp32) (relu?).
// Block 256 = 4 waves (2x2); wave tile (BM/2) x (BN/2).
// SWZ: 1-D bijective XCD-chunked grid, m-fastest (vocab: 16 x 250 blocks).
template <int BM, int BN, int BK, int BMODE, bool OUTBF, bool SWZ>
__global__ __launch_bounds__(256)
void mgemm(const short* __restrict__ A, const float* __restrict__ B,
           void* __restrict__ Cp, int M, int N, int K,
           const float* __restrict__ bias,
           const float* __restrict__ residual, int relu)
{
    constexpr int WMT = BM / 2, MI = WMT / 16, NF = BN / 32;
    constexpr int CPR = BK / 8;                 // 16B chunks per LDS row
    __shared__ short As[BM * BK];
    __shared__ short Bs[BN * BK];
    const int tid  = threadIdx.x;
    const int wave = tid >> 6, lane = tid & 63;
    const int wm = wave & 1, wn = wave >> 1;
    const int quad = lane >> 4, l16 = lane & 15;

    int m0, n0;
    if (SWZ) {
        const int wg = (blockIdx.x & 7) * 500 + (blockIdx.x >> 3);  // bijective, 4000 wgs
        m0 = (wg & 15) * BM;
        n0 = (wg >> 4) * BN;
    } else {
        m0 = blockIdx.y * BM;
        n0 = blockIdx.x * BN;
    }

    floatx4 acc[MI][NF];
#pragma unroll
    for (int i = 0; i < MI; ++i)
#pragma unroll
        for (int j = 0; j < NF; ++j)
            acc[i][j] = (floatx4){0.f, 0.f, 0.f, 0.f};

    for (int k0 = 0; k0 < K; k0 += BK) {
        __syncthreads();
        // ---- A staging: global_load_lds, source k pre-swizzled ----
#pragma unroll
        for (int s = 0; s < (BM * CPR) / 256; ++s) {
            const int c = s * 256 + tid;
            const int row = c / CPR, kp = (c % CPR) * 8;
            const int kps = kp ^ ((row & 7) << 3);
            const short* gp = A + (size_t)(m0 + row) * K + k0 + kps;
            __builtin_amdgcn_global_load_lds((gvoid*)gp, (svoid*)((char*)As + c * 16),
                                             16, 0, 0);
        }
        // ---- B staging ----
        if (BMODE == 0) {
            constexpr int QN = BN / 4;              // float4-groups along n
            constexpr int KSTEP = (256 / QN) * 4;   // k-rows per pass
            const int qn  = tid % QN;
            const int kq0 = (tid / QN) * 4;
#pragma unroll
            for (int p = 0; p < BK / KSTEP; ++p) {
                const int krow = p * KSTEP + kq0;
                const float* gp = B + (size_t)(k0 + krow) * N + n0 + qn * 4;
                const float4 r0 = *(const float4*)(gp);
                const float4 r1 = *(const float4*)(gp + N);
                const float4 r2 = *(const float4*)(gp + 2 * (size_t)N);
                const float4 r3 = *(const float4*)(gp + 3 * (size_t)N);
#pragma unroll
                for (int e = 0; e < 4; ++e) {
                    const int n = qn * 4 + e;
                    short4v p4;
                    p4.x = f2bf(e == 0 ? r0.x : e == 1 ? r0.y : e == 2 ? r0.z : r0.w);
                    p4.y = f2bf(e == 0 ? r1.x : e == 1 ? r1.y : e == 2 ? r1.z : r1.w);
                    p4.z = f2bf(e == 0 ? r2.x : e == 1 ? r2.y : e == 2 ? r2.z : r2.w);
                    p4.w = f2bf(e == 0 ? r3.x : e == 1 ? r3.y : e == 2 ? r3.z : r3.w);
                    *(short4v*)&Bs[n * BK + (krow ^ ((n & 7) << 3))] = p4;
                }
            }
        } else if (BMODE == 1) {
#pragma unroll
            for (int f = 0; f < (BN * (BK / 4)) / 256; ++f) {
                const int gidx = f * 256 + tid;
                const int n = gidx / (BK / 4), q = (gidx % (BK / 4)) * 4;
                const float4 r = *(const float4*)(B + (size_t)(n0 + n) * K + k0 + q);
                short4v p; p.x = f2bf(r.x); p.y = f2bf(r.y); p.z = f2bf(r.z); p.w = f2bf(r.w);
                *(short4v*)&Bs[n * BK + (q ^ ((n & 7) << 3))] = p;
            }
        } else {
            const short* Bb = (const short*)B;      // bf16 [N,K]
#pragma unroll
            for (int s = 0; s < (BN * CPR) / 256; ++s) {
                const int c = s * 256 + tid;
                const int row = c / CPR, kp = (c % CPR) * 8;
                const int kps = kp ^ ((row & 7) << 3);
                const short* gp = Bb + (size_t)(n0 + row) * K + k0 + kps;
                __builtin_amdgcn_global_load_lds((gvoid*)gp, (svoid*)((char*)Bs + c * 16),
                                                 16, 0, 0);
            }
        }
        __syncthreads();
        // ---- compute: 2 k-substeps of 32 ----
#pragma unroll
        for (int kk = 0; kk < BK; kk += 32) {
            short8 af[MI];
#pragma unroll
            for (int mi = 0; mi < MI; ++mi) {
                const int r = wm * WMT + mi * 16 + l16;
                af[mi] = *(short8*)&As[r * BK + ((kk + quad * 8) ^ ((r & 7) << 3))];
            }
#pragma unroll
            for (int ni = 0; ni < NF; ++ni) {
                const int n = wn * (BN / 2) + ni * 16 + l16;
                const short8 bfr = *(short8*)&Bs[n * BK + ((kk + quad * 8) ^ ((n & 7) << 3))];
#pragma unroll
                for (int mi = 0; mi < MI; ++mi)
                    acc[mi][ni] = __builtin_amdgcn_mfma_f32_16x16x32_bf16(af[mi], bfr, acc[mi][ni], 0, 0, 0);
            }
        }
    }

    // ---- epilogue ----
#pragma unroll
    for (int mi = 0; mi < MI; ++mi)
#pragma unroll
        for (int ni = 0; ni < NF; ++ni)
#pragma unroll
            for (int r = 0; r < 4; ++r) {
                const int m = m0 + wm * WMT + mi * 16 + quad * 4 + r;
                const int n = n0 + wn * (BN / 2) + ni * 16 + l16;
                float v = acc[mi][ni][r];
                if (bias)     v += bias[n];
                if (residual) v += residual[(size_t)m * N + n];
                if (relu)     v = fmaxf(v, 0.f);
                if (OUTBF) ((short*)Cp)[(size_t)m * N + n] = f2bf(v);
                else       ((float*)Cp)[(size_t)m * N + n] = v;
            }
}

// ---------------------------------------------------------------------------
// Fused QKV GEMM (BK=64, swizzled LDS): [y@wq | a@wk | a@wv] -> qkv [Mv][1536].
// BM=64, BN=64 -> grid (24, 32) = 768 blocks.
__global__ __launch_bounds__(256)
void qkv_gemm(const short* __restrict__ Aq, const short* __restrict__ Akv,
              const float* __restrict__ B0, const float* __restrict__ B1,
              const float* __restrict__ B2, short* __restrict__ QKV)
{
    constexpr int BM = 64, BN = 64, BK = 64, N = Dv, K = Dv;
    constexpr int WMT = BM / 2, MI = WMT / 16, NF = 2;
    constexpr int CPR = BK / 8;
    __shared__ short As[BM * BK];
    __shared__ short Bs[BN * BK];
    const int tid  = threadIdx.x;
    const int wave = tid >> 6, lane = tid & 63;
    const int wm = wave & 1, wn = wave >> 1;
    const int quad = lane >> 4, l16 = lane & 15;
    const int n0g = blockIdx.x * BN, m0 = blockIdx.y * BM;
    const int wsel = n0g >> 9, n0 = n0g & 511;
    const short* A = (wsel == 0) ? Aq : Akv;
    const float* B = (wsel == 0) ? B0 : (wsel == 1) ? B1 : B2;

    floatx4 acc[MI][NF];
#pragma unroll
    for (int i = 0; i < MI; ++i)
#pragma unroll
        for (int j = 0; j < NF; ++j)
            acc[i][j] = (floatx4){0.f, 0.f, 0.f, 0.f};

    for (int k0 = 0; k0 < K; k0 += BK) {
        __syncthreads();
#pragma unroll
        for (int s = 0; s < (BM * CPR) / 256; ++s) {
            const int c = s * 256 + tid;
            const int row = c / CPR, kp = (c % CPR) * 8;
            const int kps = kp ^ ((row & 7) << 3);
            const short* gp = A + (size_t)(m0 + row) * K + k0 + kps;
            __builtin_amdgcn_global_load_lds((gvoid*)gp, (svoid*)((char*)As + c * 16),
                                             16, 0, 0);
        }
        {
            constexpr int QN = BN / 4;
            const int qn  = tid % QN;
            const int krow = (tid / QN) * 4;
            const float* gp = B + (size_t)(k0 + krow) * N + n0 + qn * 4;
            const float4 r0 = *(const float4*)(gp);
            const float4 r1 = *(const float4*)(gp + N);
            const float4 r2 = *(const float4*)(gp + 2 * (size_t)N);
            const float4 r3 = *(const float4*)(gp + 3 * (size_t)N);
#pragma unroll
            for (int e = 0; e < 4; ++e) {
                const int n = qn * 4 + e;
                short4v p4;
                p4.x = f2bf(e == 0 ? r0.x : e == 1 ? r0.y : e == 2 ? r0.z : r0.w);
                p4.y = f2bf(e == 0 ? r1.x : e == 1 ? r1.y : e == 2 ? r1.z : r1.w);
                p4.z = f2bf(e == 0 ? r2.x : e == 1 ? r2.y : e == 2 ? r2.z : r2.w);
                p4.w = f2bf(e == 0 ? r3.x : e == 1 ? r3.y : e == 2 ? r3.z : r3.w);
                *(short4v*)&Bs[n * BK + (krow ^ ((n & 7) << 3))] = p4;
            }
        }
        __syncthreads();
#pragma unroll
        for (int kk = 0; kk < BK; kk += 32) {
            short8 af[MI];
#pragma unroll
            for (int mi = 0; mi < MI; ++mi) {
                const int r = wm * WMT + mi * 16 + l16;
                af[mi] = *(short8*)&As[r * BK + ((kk + quad * 8) ^ ((r & 7) << 3))];
            }
#pragma unroll
            for (int ni = 0; ni < NF; ++ni) {
                const int n = wn * 32 + ni * 16 + l16;
                const short8 bfr = *(short8*)&Bs[n * BK + ((kk + quad * 8) ^ ((n & 7) << 3))];
#pragma unroll
                for (int mi = 0; mi < MI; ++mi)
                    acc[mi][ni] = __builtin_amdgcn_mfma_f32_16x16x32_bf16(af[mi], bfr, acc[mi][ni], 0, 0, 0);
            }
        }
    }

#pragma unroll
    for (int mi = 0; mi < MI; ++mi)
#pragma unroll
        for (int ni = 0; ni < NF; ++ni)
#pragma unroll
            for (int r = 0; r < 4; ++r) {
                const int m = m0 + wm * WMT + mi * 16 + quad * 4 + r;
                const int n = n0g + wn * 32 + ni * 16 + l16;
                QKV[(size_t)m * QS + n] = f2bf(acc[mi][ni][r]);
            }
}

// ---------------------------------------------------------------------------
// Flash attention, bf16 MFMA path.  O = softmax(Q K^T / 8 (+causal)) V.
// QKV: bf16 [B*L, 1536] (q|k|v), head offset h*64.  O: bf16 [B*L, 512].
// grid (L/64, H, B); block 256 = 4 waves; each wave owns 16 query rows.
__global__ __launch_bounds__(256)
void attn_mfma(const short* __restrict__ QKV, short* __restrict__ Op, int causal)
{
    constexpr int PK = 72;                 // row pad: 144 B -> <=2-way conflicts
    __shared__ short Ks[64 * PK];
    __shared__ short Vs[64 * PK];          // transposed: Vs[d][j^swz]
    __shared__ short Ps[4][16 * PK];       // per-wave P re-fragment buffer
    const int tid  = threadIdx.x;
    const int wave = tid >> 6, lane = tid & 63;
    const int quad = lane >> 4, l16 = lane & 15;
    const int hh = blockIdx.y, bb = blockIdx.z;
    const int q0 = blockIdx.x * 64;
    const size_t base  = (size_t)bb * Lv * QS + (size_t)hh * DH;
    const short* Qp = QKV + base;
    const short* Kp = QKV + base + 512;
    const short* Vp = QKV + base + 1024;
    const size_t obase = (size_t)bb * Lv * Dv + (size_t)hh * DH;

    short8 aq[2];
    {
        const short* qp = Qp + (size_t)(q0 + wave * 16 + l16) * QS + quad * 8;
        aq[0] = *(const short8*)qp;
        aq[1] = *(const short8*)(qp + 32);
    }

    floatx4 o[4];
#pragma unroll
    for (int i = 0; i < 4; ++i) o[i] = (floatx4){0.f, 0.f, 0.f, 0.f};
    float mrow[4] = {-3.4e38f, -3.4e38f, -3.4e38f, -3.4e38f};
    float srow[4] = {0.f, 0.f, 0.f, 0.f};

    const int ntiles = causal ? (q0 / 64 + 1) : (Lv / 64);

    for (int t = 0; t < ntiles; ++t) {
        const int j0 = t * 64;
        __syncthreads();
#pragma unroll
        for (int s = 0; s < 2; ++s) {
            const int c = s * 256 + tid;
            const int j = c >> 3, off = (c & 7) * 8;
            const size_t grow = (size_t)(j0 + j) * QS + off;
            *(short8*)&Ks[j * PK + off] = *(const short8*)(Kp + grow);
            const short8 v = *(const short8*)(Vp + grow);
            const int jx = j ^ ((c & 7) << 3);     // swz = ((d>>3)&7)<<3, d=off+e
#pragma unroll
            for (int e = 0; e < 8; ++e)
                Vs[(off + e) * PK + jx] = v[e];
        }
        __syncthreads();

        // ---- S = Q K^T (4 col-frags of 16) ----
        floatx4 sf[4];
#pragma unroll
        for (int nf = 0; nf < 4; ++nf) {
            const short8 bk0 = *(const short8*)&Ks[(nf * 16 + l16) * PK + quad * 8];
            const short8 bk1 = *(const short8*)&Ks[(nf * 16 + l16) * PK + 32 + quad * 8];
            floatx4 z = (floatx4){0.f, 0.f, 0.f, 0.f};
            z = __builtin_amdgcn_mfma_f32_16x16x32_bf16(aq[0], bk0, z, 0, 0, 0);
            z = __builtin_amdgcn_mfma_f32_16x16x32_bf16(aq[1], bk1, z, 0, 0, 0);
            sf[nf] = z;
        }

        const bool mask = causal && (j0 == q0);
#pragma unroll
        for (int nf = 0; nf < 4; ++nf) {
            const int jabs = j0 + nf * 16 + l16;
#pragma unroll
            for (int r = 0; r < 4; ++r) {
                float v = sf[nf][r] * 0.125f;
                if (mask && jabs > q0 + wave * 16 + quad * 4 + r) v = NEGINF;
                sf[nf][r] = v;
            }
        }

        // ---- online softmax update ----
#pragma unroll
        for (int r = 0; r < 4; ++r) {
            float v = fmaxf(fmaxf(sf[0][r], sf[1][r]), fmaxf(sf[2][r], sf[3][r]));
            v = fmaxf(v, __shfl_xor(v, 1));
            v = fmaxf(v, __shfl_xor(v, 2));
            v = fmaxf(v, __shfl_xor(v, 4));
            v = fmaxf(v, __shfl_xor(v, 8));
            const float mnew = fmaxf(mrow[r], v);
            const float corr = __expf(mrow[r] - mnew);
            mrow[r] = mnew;
            srow[r] *= corr;
#pragma unroll
            for (int nf = 0; nf < 4; ++nf) o[nf][r] *= corr;
        }

        // ---- P = exp(S - m) -> bf16 via per-wave LDS re-fragment ----
#pragma unroll
        for (int nf = 0; nf < 4; ++nf) {
#pragma unroll
            for (int r = 0; r < 4; ++r) {
                const float pv = __expf(sf[nf][r] - mrow[r]);
                srow[r] += pv;
                Ps[wave][(quad * 4 + r) * PK + nf * 16 + l16] = f2bf(pv);
            }
        }
        __builtin_amdgcn_wave_barrier();

        // ---- O += P V ----
        const short8 pa0 = *(const short8*)&Ps[wave][l16 * PK + quad * 8];
        const short8 pa1 = *(const short8*)&Ps[wave][l16 * PK + 32 + quad * 8];
#pragma unroll
        for (int nf = 0; nf < 4; ++nf) {
            const int d   = nf * 16 + l16;
            const int swz = ((d >> 3) & 7) << 3;
            const short8 bv0 = *(const short8*)&Vs[d * PK + ((quad * 8) ^ swz)];
            const short8 bv1 = *(const short8*)&Vs[d * PK + ((32 + quad * 8) ^ swz)];
            o[nf] = __builtin_amdgcn_mfma_f32_16x16x32_bf16(pa0, bv0, o[nf], 0, 0, 0);
            o[nf] = __builtin_amdgcn_mfma_f32_16x16x32_bf16(pa1, bv1, o[nf], 0, 0, 0);
        }
    }

#pragma unroll
    for (int r = 0; r < 4; ++r) {
        float s = srow[r];
        s += __shfl_xor(s, 1);
        s += __shfl_xor(s, 2);
        s += __shfl_xor(s, 4);
        s += __shfl_xor(s, 8);
        srow[r] = 1.f / s;
    }
#pragma unroll
    for (int nf = 0; nf < 4; ++nf)
#pragma unroll
        for (int r = 0; r < 4; ++r) {
            const size_t addr = obase + (size_t)(q0 + wave * 16 + quad * 4 + r) * Dv
                              + nf * 16 + l16;
            Op[addr] = f2bf(o[nf][r] * srow[r]);
        }
}

// ---------------------------------------------------------------------------
extern "C" void kernel_launch(void* const* d_in, const int* in_sizes, int n_in,
                              void* d_out, int out_size, void* d_ws, size_t ws_size,
                              hipStream_t stream)
{
    const int*   x    = (const int*)  d_in[0];
    const float* ctx  = (const float*)d_in[1];
    const float* emb  = (const float*)d_in[2];
    const float* wq_s = (const float*)d_in[3];
    const float* wk_s = (const float*)d_in[4];
    const float* wv_s = (const float*)d_in[5];
    const float* wo_s = (const float*)d_in[6];
    const float* wq_c = (const float*)d_in[7];
    const float* wk_c = (const float*)d_in[8];
    const float* wv_c = (const float*)d_in[9];
    const float* wo_c = (const float*)d_in[10];
    const float* w1   = (const float*)d_in[11];
    const float* b1   = (const float*)d_in[12];
    const float* w2   = (const float*)d_in[13];
    const float* b2   = (const float*)d_in[14];
    const float* ln1g = (const float*)d_in[15];
    const float* ln1b = (const float*)d_in[16];
    const float* ln2g = (const float*)d_in[17];
    const float* ln2b = (const float*)d_in[18];
    const float* ln3g = (const float*)d_in[19];
    const float* ln3b = (const float*)d_in[20];
    const float* lnfg = (const float*)d_in[21];
    const float* lnfb = (const float*)d_in[22];
    float* out = (float*)d_out;

    // workspace layout:
    // [0,4M)    h fp32
    // [4,6M)    y bf16
    // [6,8M)    ao bf16
    // [8,10M)   ctx bf16
    // [10,16M)  qkv bf16 [2048][1536]   -- aliased by ff bf16 [10,18M)
    // [18,~51M) emb bf16 (if workspace allows)
    char* wsb = (char*)d_ws;
    float* h      = (float*)(wsb);
    short* y_bf   = (short*)(wsb + (4u  << 20));
    short* ao_bf  = (short*)(wsb + (6u  << 20));
    short* ctx_bf = (short*)(wsb + (8u  << 20));
    short* qkv    = (short*)(wsb + (10u << 20));
    short* ff_bf  = (short*)(wsb + (10u << 20));
    short* emb_bf = (short*)(wsb + (18u << 20));
    const bool fastv = ws_size >= (52u << 20);

    const dim3 blk(256);
    const dim3 gAttn(Lv / 64, Hv, Bv);          // 256 blocks
    const dim3 gQKV(QS / 64, Mv / 64);          // (24,32) = 768 blocks
    const dim3 gD(Dv / 64, Mv / 32);            // (8,64)  = 512 blocks (BM=32)
    const dim3 gF(Fv / 128, Mv / 64);           // (16,32) = 512 blocks
    const dim3 gV(16 * 250);                    // 4000 blocks, swizzled 1-D

    embed_kernel<<<Mv, blk, 0, stream>>>(x, emb, h);
    cvt_kernel<<<(Mv * Dv) / 1024, blk, 0, stream>>>(ctx, ctx_bf);
    if (fastv)
        cvt_kernel<<<(Vv * Dv) / 1024, blk, 0, stream>>>(emb, emb_bf);

    for (int i = 0; i < NBv; ++i) {
        const size_t wOff = (size_t)i * Dv * Dv;
        // --- self attention ---
        ln_kernel<<<Mv, blk, 0, stream>>>(h, ln1g + i * Dv, ln1b + i * Dv, y_bf);
        qkv_gemm<<<gQKV, blk, 0, stream>>>(y_bf, y_bf,
                                           wq_s + wOff, wk_s + wOff, wv_s + wOff, qkv);
        attn_mfma<<<gAttn, blk, 0, stream>>>(qkv, ao_bf, 1);
        mgemm<32, 64, 64, 0, false, false><<<gD, blk, 0, stream>>>(ao_bf, wo_s + wOff, h,
                                                                   Mv, Dv, Dv, nullptr, h, 0);
        // --- cross attention ---
        ln_kernel<<<Mv, blk, 0, stream>>>(h, ln2g + i * Dv, ln2b + i * Dv, y_bf);
        qkv_gemm<<<gQKV, blk, 0, stream>>>(y_bf, ctx_bf,
                                           wq_c + wOff, wk_c + wOff, wv_c + wOff, qkv);
        attn_mfma<<<gAttn, blk, 0, stream>>>(qkv, ao_bf, 0);
        mgemm<32, 64, 64, 0, false, false><<<gD, blk, 0, stream>>>(ao_bf, wo_c + wOff, h,
                                                                   Mv, Dv, Dv, nullptr, h, 0);
        // --- feed forward ---
        ln_kernel<<<Mv, blk, 0, stream>>>(h, ln3g + i * Dv, ln3b + i * Dv, y_bf);
        mgemm<64, 128, 64, 0, true, false><<<gF, blk, 0, stream>>>(y_bf, w1 + (size_t)i * Dv * Fv,
                                                                   ff_bf, Mv, Fv, Dv,
                                                                   b1 + (size_t)i * Fv, nullptr, 1);
        mgemm<32, 64, 64, 0, false, false><<<gD, blk, 0, stream>>>(ff_bf, w2 + (size_t)i * Fv * Dv,
                                                                   h, Mv, Dv, Fv,
                                                                   b2 + (size_t)i * Dv, h, 0);
    }

    ln_kernel<<<Mv, blk, 0, stream>>>(h, lnfg, lnfb, y_bf);
    if (fastv)
        mgemm<128, 128, 64, 2, false, true><<<gV, blk, 0, stream>>>(y_bf, (const float*)emb_bf,
                                                                    out, Mv, Vv, Dv,
                                                                    nullptr, nullptr, 0);
    else
        mgemm<128, 128, 64, 1, false, true><<<gV, blk, 0, stream>>>(y_bf, emb, out,
                                                                    Mv, Vv, Dv,
                                                                    nullptr, nullptr, 0);
}

// Round 4
// 1406.665 us; speedup vs baseline: 3.7245x; 1.1879x over previous
//
#include <hip/hip_runtime.h>
#include <math.h>

// Problem constants
#define Bv 2
#define Lv 1024
#define Dv 512
#define Hv 8
#define DH 64
#define Fv 2048
#define NBv 6
#define Vv 32000
#define Mv (Bv*Lv)          // 2048 rows
#define QS 1536             // fused qkv row stride (q|k|v concat)
#define KVS 6144            // packed cross-KV row stride (6 layers x (K|V))
#define NEGINF -1e10f

typedef __attribute__((ext_vector_type(8))) short short8;   // 8 bf16
typedef __attribute__((ext_vector_type(4))) short short4v;  // 4 bf16
typedef __attribute__((ext_vector_type(4))) float floatx4;
typedef __attribute__((address_space(1))) const void gvoid;
typedef __attribute__((address_space(3))) void svoid;

__device__ __forceinline__ short f2bf(float f) {
    union { float f; unsigned u; } v; v.f = f;
    unsigned r = v.u + 0x7fffu + ((v.u >> 16) & 1u);   // RNE
    return (short)(r >> 16);
}

// ---------------------------------------------------------------------------
// Embedding + sinusoidal positional encoding (fp32 h)
__global__ __launch_bounds__(256)
void embed_kernel(const int* __restrict__ xi, const float* __restrict__ emb,
                  float* __restrict__ h)
{
    const int row = blockIdx.x;
    const int l   = row & (Lv - 1);
    const int tok = xi[row];
    const int tid = threadIdx.x;
#pragma unroll
    for (int s = 0; s < 2; ++s) {
        const int d  = tid + s * 256;
        const int dd = d & 255;
        const float freq = powf(10000.f, (float)dd * (1.f / 256.f));
        const float arg  = (float)l / freq;
        const float pe   = (d < 256) ? sinf(arg) : cosf(arg);
        h[(size_t)row * Dv + d] = emb[(size_t)tok * Dv + d] * 22.62741699796952f + pe;
    }
}

// ---------------------------------------------------------------------------
// fp32 -> bf16 convert
__global__ __launch_bounds__(256)
void cvt_kernel(const float* __restrict__ X, short* __restrict__ Y)
{
    const int i = (blockIdx.x * 256 + threadIdx.x) * 4;
    const float4 v = *(const float4*)(X + i);
    short4v p; p.x = f2bf(v.x); p.y = f2bf(v.y); p.z = f2bf(v.z); p.w = f2bf(v.w);
    *(short4v*)(Y + i) = p;
}

// ---------------------------------------------------------------------------
// Batched transpose + convert: src fp32 [z][K][N] -> dst bf16 [z][N][K]
// dst element (n,k) of slab z at: dst + z*dstZ + dstOff + n*K + k.
// grid (N/64, K/64, count), 256 threads, LDS 64x65 fp32 tile.
__global__ __launch_bounds__(256)
void tr_cvt(const float* __restrict__ src, short* __restrict__ dst,
            int K, int N, size_t dstZ, size_t dstOff)
{
    __shared__ float t[64][65];
    const int z  = blockIdx.z;
    const int n0 = blockIdx.x * 64, k0 = blockIdx.y * 64;
    const int tid = threadIdx.x;
    const float* s = src + (size_t)z * K * N;
    short* d = dst + (size_t)z * dstZ + dstOff;

    const int kr = tid >> 2, nc = (tid & 3) * 16;
#pragma unroll
    for (int j = 0; j < 16; j += 4) {
        const float4 v = *(const float4*)(s + (size_t)(k0 + kr) * N + n0 + nc + j);
        t[kr][nc + j + 0] = v.x; t[kr][nc + j + 1] = v.y;
        t[kr][nc + j + 2] = v.z; t[kr][nc + j + 3] = v.w;
    }
    __syncthreads();
    const int nr = tid >> 2, kc = (tid & 3) * 16;
    short8 o0, o1;
#pragma unroll
    for (int j = 0; j < 8; ++j)  o0[j] = f2bf(t[kc + j][nr]);
#pragma unroll
    for (int j = 0; j < 8; ++j)  o1[j] = f2bf(t[kc + 8 + j][nr]);
    *(short8*)(d + (size_t)(n0 + nr) * K + k0 + kc)     = o0;
    *(short8*)(d + (size_t)(n0 + nr) * K + k0 + kc + 8) = o1;
}

// ---------------------------------------------------------------------------
// LayerNorm: one block per row, 256 threads, D=512; bf16 output
__global__ __launch_bounds__(256)
void ln_kernel(const float* __restrict__ X, const float* __restrict__ g,
               const float* __restrict__ bta, short* __restrict__ Y)
{
    const int row = blockIdx.x, tid = threadIdx.x;
    const float* xr = X + (size_t)row * Dv;
    const float x0 = xr[tid], x1 = xr[tid + 256];
    __shared__ float red[4];

    float s = x0 + x1;
#pragma unroll
    for (int off = 32; off; off >>= 1) s += __shfl_xor(s, off);
    if ((tid & 63) == 0) red[tid >> 6] = s;
    __syncthreads();
    const float mean = (red[0] + red[1] + red[2] + red[3]) * (1.f / Dv);
    __syncthreads();

    const float d0 = x0 - mean, d1 = x1 - mean;
    float v = d0 * d0 + d1 * d1;
#pragma unroll
    for (int off = 32; off; off >>= 1) v += __shfl_xor(v, off);
    if ((tid & 63) == 0) red[tid >> 6] = v;
    __syncthreads();
    const float var  = (red[0] + red[1] + red[2] + red[3]) * (1.f / Dv);
    const float rstd = rsqrtf(var + 1e-6f);

    Y[(size_t)row * Dv + tid]       = f2bf(d0 * rstd * g[tid]       + bta[tid]);
    Y[(size_t)row * Dv + tid + 256] = f2bf(d1 * rstd * g[tid + 256] + bta[tid + 256]);
}

// ---------------------------------------------------------------------------
// bf16 MFMA GEMM, BK=64, XOR-swizzled LDS (col8 ^ ((row&7)<<3) in shorts).
// A: bf16 [M,K] rm via global_load_lds with pre-swizzled source.
// BMODE 0: B fp32 [K,N] rm (VALU convert, swizzled stores)
// BMODE 1: B fp32 [N,K] rm (VALU convert, swizzled stores)
// BMODE 2: B bf16 [N,K] rm (global_load_lds, pre-swizzled source)
// DBUF (BMODE2 only): 2-phase double-buffered K-loop — prefetch tile t+1
// while computing tile t, one barrier per tile.
// C = A@B (+bias) (+residual fp32) (relu?).
// Block 256 = 4 waves (2x2); wave tile (BM/2) x (BN/2).
// SWZ: 1-D bijective XCD-chunked grid, m-fastest (vocab: 16 x 250 blocks).
template <int BM, int BN, int BK, int BMODE, bool OUTBF, bool SWZ, bool DBUF>
__global__ __launch_bounds__(256)
void mgemm(const short* __restrict__ A, const float* __restrict__ B,
           void* __restrict__ Cp, int M, int N, int K,
           const float* __restrict__ bias,
           const float* __restrict__ residual, int relu)
{
    constexpr int WMT = BM / 2, MI = WMT / 16, NF = BN / 32;
    constexpr int CPR = BK / 8;                 // 16B chunks per LDS row
    constexpr int NBUF = (DBUF && BMODE == 2) ? 2 : 1;
    __shared__ short As[NBUF * BM * BK];
    __shared__ short Bs[NBUF * BN * BK];
    const int tid  = threadIdx.x;
    const int wave = tid >> 6, lane = tid & 63;
    const int wm = wave & 1, wn = wave >> 1;
    const int quad = lane >> 4, l16 = lane & 15;

    int m0, n0;
    if (SWZ) {
        const int wg = (blockIdx.x & 7) * 500 + (blockIdx.x >> 3);  // bijective, 4000 wgs
        m0 = (wg & 15) * BM;
        n0 = (wg >> 4) * BN;
    } else {
        m0 = blockIdx.y * BM;
        n0 = blockIdx.x * BN;
    }

    floatx4 acc[MI][NF];
#pragma unroll
    for (int i = 0; i < MI; ++i)
#pragma unroll
        for (int j = 0; j < NF; ++j)
            acc[i][j] = (floatx4){0.f, 0.f, 0.f, 0.f};

    auto computeTile = [&](const short* Asb, const short* Bsb) {
#pragma unroll
        for (int kk = 0; kk < BK; kk += 32) {
            short8 af[MI];
#pragma unroll
            for (int mi = 0; mi < MI; ++mi) {
                const int r = wm * WMT + mi * 16 + l16;
                af[mi] = *(const short8*)&Asb[r * BK + ((kk + quad * 8) ^ ((r & 7) << 3))];
            }
#pragma unroll
            for (int ni = 0; ni < NF; ++ni) {
                const int n = wn * (BN / 2) + ni * 16 + l16;
                const short8 bfr = *(const short8*)&Bsb[n * BK + ((kk + quad * 8) ^ ((n & 7) << 3))];
#pragma unroll
                for (int mi = 0; mi < MI; ++mi)
                    acc[mi][ni] = __builtin_amdgcn_mfma_f32_16x16x32_bf16(af[mi], bfr, acc[mi][ni], 0, 0, 0);
            }
        }
    };

    if constexpr (DBUF && BMODE == 2) {
        const short* Bb = (const short*)B;
        auto stage = [&](int buf, int kbase) {
#pragma unroll
            for (int s = 0; s < (BM * CPR) / 256; ++s) {
                const int c = s * 256 + tid;
                const int row = c / CPR, kp = (c % CPR) * 8;
                const int kps = kp ^ ((row & 7) << 3);
                const short* gp = A + (size_t)(m0 + row) * K + kbase + kps;
                __builtin_amdgcn_global_load_lds((gvoid*)gp,
                    (svoid*)((char*)As + buf * (BM * BK * 2) + c * 16), 16, 0, 0);
            }
#pragma unroll
            for (int s = 0; s < (BN * CPR) / 256; ++s) {
                const int c = s * 256 + tid;
                const int row = c / CPR, kp = (c % CPR) * 8;
                const int kps = kp ^ ((row & 7) << 3);
                const short* gp = Bb + (size_t)(n0 + row) * K + kbase + kps;
                __builtin_amdgcn_global_load_lds((gvoid*)gp,
                    (svoid*)((char*)Bs + buf * (BN * BK * 2) + c * 16), 16, 0, 0);
            }
        };
        stage(0, 0);
        __syncthreads();
        const int NT = K / BK;
        for (int t = 0; t < NT; ++t) {
            const int cur = t & 1;
            if (t + 1 < NT) stage(cur ^ 1, (t + 1) * BK);
            computeTile(As + cur * BM * BK, Bs + cur * BN * BK);
            __syncthreads();      // drains prefetch vmcnt + protects buf reuse
        }
    } else {
        for (int k0 = 0; k0 < K; k0 += BK) {
            __syncthreads();
            // ---- A staging: global_load_lds, source k pre-swizzled ----
#pragma unroll
            for (int s = 0; s < (BM * CPR) / 256; ++s) {
                const int c = s * 256 + tid;
                const int row = c / CPR, kp = (c % CPR) * 8;
                const int kps = kp ^ ((row & 7) << 3);
                const short* gp = A + (size_t)(m0 + row) * K + k0 + kps;
                __builtin_amdgcn_global_load_lds((gvoid*)gp, (svoid*)((char*)As + c * 16),
                                                 16, 0, 0);
            }
            // ---- B staging ----
            if (BMODE == 0) {
                constexpr int QN = BN / 4;              // float4-groups along n
                constexpr int KSTEP = (256 / QN) * 4;   // k-rows per pass
                const int qn  = tid % QN;
                const int kq0 = (tid / QN) * 4;
#pragma unroll
                for (int p = 0; p < BK / KSTEP; ++p) {
                    const int krow = p * KSTEP + kq0;
                    const float* gp = B + (size_t)(k0 + krow) * N + n0 + qn * 4;
                    const float4 r0 = *(const float4*)(gp);
                    const float4 r1 = *(const float4*)(gp + N);
                    const float4 r2 = *(const float4*)(gp + 2 * (size_t)N);
                    const float4 r3 = *(const float4*)(gp + 3 * (size_t)N);
#pragma unroll
                    for (int e = 0; e < 4; ++e) {
                        const int n = qn * 4 + e;
                        short4v p4;
                        p4.x = f2bf(e == 0 ? r0.x : e == 1 ? r0.y : e == 2 ? r0.z : r0.w);
                        p4.y = f2bf(e == 0 ? r1.x : e == 1 ? r1.y : e == 2 ? r1.z : r1.w);
                        p4.z = f2bf(e == 0 ? r2.x : e == 1 ? r2.y : e == 2 ? r2.z : r2.w);
                        p4.w = f2bf(e == 0 ? r3.x : e == 1 ? r3.y : e == 2 ? r3.z : r3.w);
                        *(short4v*)&Bs[n * BK + (krow ^ ((n & 7) << 3))] = p4;
                    }
                }
            } else if (BMODE == 1) {
#pragma unroll
                for (int f = 0; f < (BN * (BK / 4)) / 256; ++f) {
                    const int gidx = f * 256 + tid;
                    const int n = gidx / (BK / 4), q = (gidx % (BK / 4)) * 4;
                    const float4 r = *(const float4*)(B + (size_t)(n0 + n) * K + k0 + q);
                    short4v p; p.x = f2bf(r.x); p.y = f2bf(r.y); p.z = f2bf(r.z); p.w = f2bf(r.w);
                    *(short4v*)&Bs[n * BK + (q ^ ((n & 7) << 3))] = p;
                }
            } else {
                const short* Bb = (const short*)B;      // bf16 [N,K]
#pragma unroll
                for (int s = 0; s < (BN * CPR) / 256; ++s) {
                    const int c = s * 256 + tid;
                    const int row = c / CPR, kp = (c % CPR) * 8;
                    const int kps = kp ^ ((row & 7) << 3);
                    const short* gp = Bb + (size_t)(n0 + row) * K + k0 + kps;
                    __builtin_amdgcn_global_load_lds((gvoid*)gp, (svoid*)((char*)Bs + c * 16),
                                                     16, 0, 0);
                }
            }
            __syncthreads();
            computeTile(As, Bs);
        }
    }

    // ---- epilogue ----
#pragma unroll
    for (int mi = 0; mi < MI; ++mi)
#pragma unroll
        for (int ni = 0; ni < NF; ++ni)
#pragma unroll
            for (int r = 0; r < 4; ++r) {
                const int m = m0 + wm * WMT + mi * 16 + quad * 4 + r;
                const int n = n0 + wn * (BN / 2) + ni * 16 + l16;
                float v = acc[mi][ni][r];
                if (bias)     v += bias[n];
                if (residual) v += residual[(size_t)m * N + n];
                if (relu)     v = fmaxf(v, 0.f);
                if (OUTBF) ((short*)Cp)[(size_t)m * N + n] = f2bf(v);
                else       ((float*)Cp)[(size_t)m * N + n] = v;
            }
}

// ---------------------------------------------------------------------------
// Fused QKV GEMM (fallback path only; BK=64, swizzled LDS).
__global__ __launch_bounds__(256)
void qkv_gemm(const short* __restrict__ Aq, const short* __restrict__ Akv,
              const float* __restrict__ B0, const float* __restrict__ B1,
              const float* __restrict__ B2, short* __restrict__ QKV)
{
    constexpr int BM = 64, BN = 64, BK = 64, N = Dv, K = Dv;
    constexpr int WMT = BM / 2, MI = WMT / 16, NF = 2;
    constexpr int CPR = BK / 8;
    __shared__ short As[BM * BK];
    __shared__ short Bs[BN * BK];
    const int tid  = threadIdx.x;
    const int wave = tid >> 6, lane = tid & 63;
    const int wm = wave & 1, wn = wave >> 1;
    const int quad = lane >> 4, l16 = lane & 15;
    const int n0g = blockIdx.x * BN, m0 = blockIdx.y * BM;
    const int wsel = n0g >> 9, n0 = n0g & 511;
    const short* A = (wsel == 0) ? Aq : Akv;
    const float* B = (wsel == 0) ? B0 : (wsel == 1) ? B1 : B2;

    floatx4 acc[MI][NF];
#pragma unroll
    for (int i = 0; i < MI; ++i)
#pragma unroll
        for (int j = 0; j < NF; ++j)
            acc[i][j] = (floatx4){0.f, 0.f, 0.f, 0.f};

    for (int k0 = 0; k0 < K; k0 += BK) {
        __syncthreads();
#pragma unroll
        for (int s = 0; s < (BM * CPR) / 256; ++s) {
            const int c = s * 256 + tid;
            const int row = c / CPR, kp = (c % CPR) * 8;
            const int kps = kp ^ ((row & 7) << 3);
            const short* gp = A + (size_t)(m0 + row) * K + k0 + kps;
            __builtin_amdgcn_global_load_lds((gvoid*)gp, (svoid*)((char*)As + c * 16),
                                             16, 0, 0);
        }
        {
            constexpr int QN = BN / 4;
            const int qn  = tid % QN;
            const int krow = (tid / QN) * 4;
            const float* gp = B + (size_t)(k0 + krow) * N + n0 + qn * 4;
            const float4 r0 = *(const float4*)(gp);
            const float4 r1 = *(const float4*)(gp + N);
            const float4 r2 = *(const float4*)(gp + 2 * (size_t)N);
            const float4 r3 = *(const float4*)(gp + 3 * (size_t)N);
#pragma unroll
            for (int e = 0; e < 4; ++e) {
                const int n = qn * 4 + e;
                short4v p4;
                p4.x = f2bf(e == 0 ? r0.x : e == 1 ? r0.y : e == 2 ? r0.z : r0.w);
                p4.y = f2bf(e == 0 ? r1.x : e == 1 ? r1.y : e == 2 ? r1.z : r1.w);
                p4.z = f2bf(e == 0 ? r2.x : e == 1 ? r2.y : e == 2 ? r2.z : r2.w);
                p4.w = f2bf(e == 0 ? r3.x : e == 1 ? r3.y : e == 2 ? r3.z : r3.w);
                *(short4v*)&Bs[n * BK + (krow ^ ((n & 7) << 3))] = p4;
            }
        }
        __syncthreads();
#pragma unroll
        for (int kk = 0; kk < BK; kk += 32) {
            short8 af[MI];
#pragma unroll
            for (int mi = 0; mi < MI; ++mi) {
                const int r = wm * WMT + mi * 16 + l16;
                af[mi] = *(short8*)&As[r * BK + ((kk + quad * 8) ^ ((r & 7) << 3))];
            }
#pragma unroll
            for (int ni = 0; ni < NF; ++ni) {
                const int n = wn * 32 + ni * 16 + l16;
                const short8 bfr = *(short8*)&Bs[n * BK + ((kk + quad * 8) ^ ((n & 7) << 3))];
#pragma unroll
                for (int mi = 0; mi < MI; ++mi)
                    acc[mi][ni] = __builtin_amdgcn_mfma_f32_16x16x32_bf16(af[mi], bfr, acc[mi][ni], 0, 0, 0);
            }
        }
    }

#pragma unroll
    for (int mi = 0; mi < MI; ++mi)
#pragma unroll
        for (int ni = 0; ni < NF; ++ni)
#pragma unroll
            for (int r = 0; r < 4; ++r) {
                const int m = m0 + wm * WMT + mi * 16 + quad * 4 + r;
                const int n = n0g + wn * 32 + ni * 16 + l16;
                QKV[(size_t)m * QS + n] = f2bf(acc[mi][ni][r]);
            }
}

// ---------------------------------------------------------------------------
// Flash attention, bf16 MFMA path.  O = softmax(Q K^T / 8 (+causal)) V.
// Q: bf16 rows stride qstr; K,V: bf16 rows stride kvstr. O: bf16 [B*L, 512].
// grid (L/64, H, B); block 256 = 4 waves; each wave owns 16 query rows.
__global__ __launch_bounds__(256)
void attn_mfma(const short* __restrict__ Qp, int qstr,
               const short* __restrict__ Kp, const short* __restrict__ Vp, int kvstr,
               short* __restrict__ Op, int causal)
{
    constexpr int PK = 72;                 // row pad: 144 B -> <=2-way conflicts
    __shared__ short Ks[64 * PK];
    __shared__ short Vs[64 * PK];          // transposed: Vs[d][j^swz]
    __shared__ short Ps[4][16 * PK];       // per-wave P re-fragment buffer
    const int tid  = threadIdx.x;
    const int wave = tid >> 6, lane = tid & 63;
    const int quad = lane >> 4, l16 = lane & 15;
    const int hh = blockIdx.y, bb = blockIdx.z;
    const int q0 = blockIdx.x * 64;
    const size_t qbase  = (size_t)bb * Lv * qstr  + (size_t)hh * DH;
    const size_t kvbase = (size_t)bb * Lv * kvstr + (size_t)hh * DH;
    const size_t obase  = (size_t)bb * Lv * Dv + (size_t)hh * DH;

    short8 aq[2];
    {
        const short* qp = Qp + qbase + (size_t)(q0 + wave * 16 + l16) * qstr + quad * 8;
        aq[0] = *(const short8*)qp;
        aq[1] = *(const short8*)(qp + 32);
    }

    floatx4 o[4];
#pragma unroll
    for (int i = 0; i < 4; ++i) o[i] = (floatx4){0.f, 0.f, 0.f, 0.f};
    float mrow[4] = {-3.4e38f, -3.4e38f, -3.4e38f, -3.4e38f};
    float srow[4] = {0.f, 0.f, 0.f, 0.f};

    const int ntiles = causal ? (q0 / 64 + 1) : (Lv / 64);

    for (int t = 0; t < ntiles; ++t) {
        const int j0 = t * 64;
        __syncthreads();
#pragma unroll
        for (int s = 0; s < 2; ++s) {
            const int c = s * 256 + tid;
            const int j = c >> 3, off = (c & 7) * 8;
            const size_t grow = kvbase + (size_t)(j0 + j) * kvstr + off;
            *(short8*)&Ks[j * PK + off] = *(const short8*)(Kp + grow);
            const short8 v = *(const short8*)(Vp + grow);
            const int jx = j ^ ((c & 7) << 3);     // swz = ((d>>3)&7)<<3, d=off+e
#pragma unroll
            for (int e = 0; e < 8; ++e)
                Vs[(off + e) * PK + jx] = v[e];
        }
        __syncthreads();

        // ---- S = Q K^T (4 col-frags of 16) ----
        floatx4 sf[4];
#pragma unroll
        for (int nf = 0; nf < 4; ++nf) {
            const short8 bk0 = *(const short8*)&Ks[(nf * 16 + l16) * PK + quad * 8];
            const short8 bk1 = *(const short8*)&Ks[(nf * 16 + l16) * PK + 32 + quad * 8];
            floatx4 z = (floatx4){0.f, 0.f, 0.f, 0.f};
            z = __builtin_amdgcn_mfma_f32_16x16x32_bf16(aq[0], bk0, z, 0, 0, 0);
            z = __builtin_amdgcn_mfma_f32_16x16x32_bf16(aq[1], bk1, z, 0, 0, 0);
            sf[nf] = z;
        }

        const bool mask = causal && (j0 == q0);
#pragma unroll
        for (int nf = 0; nf < 4; ++nf) {
            const int jabs = j0 + nf * 16 + l16;
#pragma unroll
            for (int r = 0; r < 4; ++r) {
                float v = sf[nf][r] * 0.125f;
                if (mask && jabs > q0 + wave * 16 + quad * 4 + r) v = NEGINF;
                sf[nf][r] = v;
            }
        }

        // ---- online softmax update ----
#pragma unroll
        for (int r = 0; r < 4; ++r) {
            float v = fmaxf(fmaxf(sf[0][r], sf[1][r]), fmaxf(sf[2][r], sf[3][r]));
            v = fmaxf(v, __shfl_xor(v, 1));
            v = fmaxf(v, __shfl_xor(v, 2));
            v = fmaxf(v, __shfl_xor(v, 4));
            v = fmaxf(v, __shfl_xor(v, 8));
            const float mnew = fmaxf(mrow[r], v);
            const float corr = __expf(mrow[r] - mnew);
            mrow[r] = mnew;
            srow[r] *= corr;
#pragma unroll
            for (int nf = 0; nf < 4; ++nf) o[nf][r] *= corr;
        }

        // ---- P = exp(S - m) -> bf16 via per-wave LDS re-fragment ----
#pragma unroll
        for (int nf = 0; nf < 4; ++nf) {
#pragma unroll
            for (int r = 0; r < 4; ++r) {
                const float pv = __expf(sf[nf][r] - mrow[r]);
                srow[r] += pv;
                Ps[wave][(quad * 4 + r) * PK + nf * 16 + l16] = f2bf(pv);
            }
        }
        __builtin_amdgcn_wave_barrier();

        // ---- O += P V ----
        const short8 pa0 = *(const short8*)&Ps[wave][l16 * PK + quad * 8];
        const short8 pa1 = *(const short8*)&Ps[wave][l16 * PK + 32 + quad * 8];
#pragma unroll
        for (int nf = 0; nf < 4; ++nf) {
            const int d   = nf * 16 + l16;
            const int swz = ((d >> 3) & 7) << 3;
            const short8 bv0 = *(const short8*)&Vs[d * PK + ((quad * 8) ^ swz)];
            const short8 bv1 = *(const short8*)&Vs[d * PK + ((32 + quad * 8) ^ swz)];
            o[nf] = __builtin_amdgcn_mfma_f32_16x16x32_bf16(pa0, bv0, o[nf], 0, 0, 0);
            o[nf] = __builtin_amdgcn_mfma_f32_16x16x32_bf16(pa1, bv1, o[nf], 0, 0, 0);
        }
    }

#pragma unroll
    for (int r = 0; r < 4; ++r) {
        float s = srow[r];
        s += __shfl_xor(s, 1);
        s += __shfl_xor(s, 2);
        s += __shfl_xor(s, 4);
        s += __shfl_xor(s, 8);
        srow[r] = 1.f / s;
    }
#pragma unroll
    for (int nf = 0; nf < 4; ++nf)
#pragma unroll
        for (int r = 0; r < 4; ++r) {
            const size_t addr = obase + (size_t)(q0 + wave * 16 + quad * 4 + r) * Dv
                              + nf * 16 + l16;
            Op[addr] = f2bf(o[nf][r] * srow[r]);
        }
}

// ---------------------------------------------------------------------------
extern "C" void kernel_launch(void* const* d_in, const int* in_sizes, int n_in,
                              void* d_out, int out_size, void* d_ws, size_t ws_size,
                              hipStream_t stream)
{
    const int*   x    = (const int*)  d_in[0];
    const float* ctx  = (const float*)d_in[1];
    const float* emb  = (const float*)d_in[2];
    const float* wq_s = (const float*)d_in[3];
    const float* wk_s = (const float*)d_in[4];
    const float* wv_s = (const float*)d_in[5];
    const float* wo_s = (const float*)d_in[6];
    const float* wq_c = (const float*)d_in[7];
    const float* wk_c = (const float*)d_in[8];
    const float* wv_c = (const float*)d_in[9];
    const float* wo_c = (const float*)d_in[10];
    const float* w1   = (const float*)d_in[11];
    const float* b1   = (const float*)d_in[12];
    const float* w2   = (const float*)d_in[13];
    const float* b2   = (const float*)d_in[14];
    const float* ln1g = (const float*)d_in[15];
    const float* ln1b = (const float*)d_in[16];
    const float* ln2g = (const float*)d_in[17];
    const float* ln2b = (const float*)d_in[18];
    const float* ln3g = (const float*)d_in[19];
    const float* ln3b = (const float*)d_in[20];
    const float* lnfg = (const float*)d_in[21];
    const float* lnfb = (const float*)d_in[22];
    float* out = (float*)d_out;

    char* wsb = (char*)d_ws;
    const dim3 blk(256);
    const dim3 gAttn(Lv / 64, Hv, Bv);          // 256 blocks
    const dim3 gV(16 * 250);                    // 4000 blocks, swizzled 1-D

    if (ws_size >= (150u << 20)) {
        // ---------------- fast path: bf16 [N,K] weights + dbuf GEMMs --------
        // layout (MB): h 0..4 | y 4..6 | ao 6..8 | ctx_bf 8..10 | qkv 10..16 |
        // ff 16..24 | qb 24..26 | kvc 26..50 | wqkv_s 50..60 | wo_s_t 60..64 |
        // wq_c_t 64..68 | wo_c_t 68..72 | kvw 72..79 | w1t 79..92 | w2t 92..105 |
        // emb_bf 105..138
        float* h      = (float*)(wsb);
        short* y_bf   = (short*)(wsb + (4u   << 20));
        short* ao_bf  = (short*)(wsb + (6u   << 20));
        short* ctx_bf = (short*)(wsb + (8u   << 20));
        short* qkv    = (short*)(wsb + (10u  << 20));
        short* ff_bf  = (short*)(wsb + (16u  << 20));
        short* qb     = (short*)(wsb + (24u  << 20));
        short* kvc    = (short*)(wsb + (26u  << 20));
        short* wqkv_s = (short*)(wsb + (50u  << 20));
        short* wo_s_t = (short*)(wsb + (60u  << 20));
        short* wq_c_t = (short*)(wsb + (64u  << 20));
        short* wo_c_t = (short*)(wsb + (68u  << 20));
        short* kvw    = (short*)(wsb + (72u  << 20));
        short* w1t    = (short*)(wsb + (79u  << 20));
        short* w2t    = (short*)(wsb + (92u  << 20));
        short* emb_bf = (short*)(wsb + (105u << 20));

        embed_kernel<<<Mv, blk, 0, stream>>>(x, emb, h);
        cvt_kernel<<<(Mv * Dv) / 1024, blk, 0, stream>>>(ctx, ctx_bf);
        cvt_kernel<<<(Vv * Dv) / 1024, blk, 0, stream>>>(emb, emb_bf);

        // weight transposes (fp32 [K,N] -> bf16 [N,K]), batched over 6 layers
        const dim3 gT55(8, 8, NBv);                 // 512x512
        const dim3 gT5F(Fv / 64, 8, NBv);           // K=512,N=2048 (w1)
        const dim3 gTF5(8, Fv / 64, NBv);           // K=2048,N=512 (w2)
        tr_cvt<<<gT55, blk, 0, stream>>>(wq_s, wqkv_s, Dv, Dv, (size_t)QS * Dv, 0);
        tr_cvt<<<gT55, blk, 0, stream>>>(wk_s, wqkv_s, Dv, Dv, (size_t)QS * Dv, (size_t)Dv * Dv);
        tr_cvt<<<gT55, blk, 0, stream>>>(wv_s, wqkv_s, Dv, Dv, (size_t)QS * Dv, (size_t)2 * Dv * Dv);
        tr_cvt<<<gT55, blk, 0, stream>>>(wo_s, wo_s_t, Dv, Dv, (size_t)Dv * Dv, 0);
        tr_cvt<<<gT55, blk, 0, stream>>>(wq_c, wq_c_t, Dv, Dv, (size_t)Dv * Dv, 0);
        tr_cvt<<<gT55, blk, 0, stream>>>(wo_c, wo_c_t, Dv, Dv, (size_t)Dv * Dv, 0);
        tr_cvt<<<gT55, blk, 0, stream>>>(wk_c, kvw, Dv, Dv, (size_t)2 * Dv * Dv, 0);
        tr_cvt<<<gT55, blk, 0, stream>>>(wv_c, kvw, Dv, Dv, (size_t)2 * Dv * Dv, (size_t)Dv * Dv);
        tr_cvt<<<gT5F, blk, 0, stream>>>(w1, w1t, Dv, Fv, (size_t)Fv * Dv, 0);
        tr_cvt<<<gTF5, blk, 0, stream>>>(w2, w2t, Fv, Dv, (size_t)Dv * Fv, 0);

        // batched cross K/V for all layers: ctx_bf @ kvw^T -> kvc [2048][6144]
        {
            const dim3 g(KVS / 64, Mv / 128);
            mgemm<128, 64, 64, 2, true, false, true><<<g, blk, 0, stream>>>(
                ctx_bf, (const float*)kvw, kvc, Mv, KVS, Dv, nullptr, nullptr, 0);
        }

        const dim3 gQKV(QS / 64, Mv / 64);          // (24,32)
        const dim3 gD(Dv / 64, Mv / 32);            // (8,64)  BM=32
        const dim3 gF1(Fv / 128, Mv / 64);          // (16,32) BM=64,BN=128

        for (int i = 0; i < NBv; ++i) {
            // --- self attention ---
            ln_kernel<<<Mv, blk, 0, stream>>>(h, ln1g + i * Dv, ln1b + i * Dv, y_bf);
            mgemm<64, 64, 64, 2, true, false, true><<<gQKV, blk, 0, stream>>>(
                y_bf, (const float*)(wqkv_s + (size_t)i * QS * Dv), qkv,
                Mv, QS, Dv, nullptr, nullptr, 0);
            attn_mfma<<<gAttn, blk, 0, stream>>>(qkv, QS, qkv + 512, qkv + 1024, QS, ao_bf, 1);
            mgemm<32, 64, 64, 2, false, false, true><<<gD, blk, 0, stream>>>(
                ao_bf, (const float*)(wo_s_t + (size_t)i * Dv * Dv), h,
                Mv, Dv, Dv, nullptr, h, 0);
            // --- cross attention ---
            ln_kernel<<<Mv, blk, 0, stream>>>(h, ln2g + i * Dv, ln2b + i * Dv, y_bf);
            mgemm<32, 64, 64, 2, true, false, true><<<gD, blk, 0, stream>>>(
                y_bf, (const float*)(wq_c_t + (size_t)i * Dv * Dv), qb,
                Mv, Dv, Dv, nullptr, nullptr, 0);
            attn_mfma<<<gAttn, blk, 0, stream>>>(qb, Dv,
                kvc + (size_t)i * 1024, kvc + (size_t)i * 1024 + 512, KVS, ao_bf, 0);
            mgemm<32, 64, 64, 2, false, false, true><<<gD, blk, 0, stream>>>(
                ao_bf, (const float*)(wo_c_t + (size_t)i * Dv * Dv), h,
                Mv, Dv, Dv, nullptr, h, 0);
            // --- feed forward ---
            ln_kernel<<<Mv, blk, 0, stream>>>(h, ln3g + i * Dv, ln3b + i * Dv, y_bf);
            mgemm<64, 128, 64, 2, true, false, true><<<gF1, blk, 0, stream>>>(
                y_bf, (const float*)(w1t + (size_t)i * Fv * Dv), ff_bf,
                Mv, Fv, Dv, b1 + (size_t)i * Fv, nullptr, 1);
            mgemm<32, 64, 64, 2, false, false, true><<<gD, blk, 0, stream>>>(
                ff_bf, (const float*)(w2t + (size_t)i * Dv * Fv), h,
                Mv, Dv, Fv, b2 + (size_t)i * Dv, h, 0);
        }

        ln_kernel<<<Mv, blk, 0, stream>>>(h, lnfg, lnfb, y_bf);
        mgemm<128, 128, 64, 2, false, true, false><<<gV, blk, 0, stream>>>(
            y_bf, (const float*)emb_bf, out, Mv, Vv, Dv, nullptr, nullptr, 0);
    } else {
        // ---------------- fallback: round-3 path ----------------------------
        float* h      = (float*)(wsb);
        short* y_bf   = (short*)(wsb + (4u  << 20));
        short* ao_bf  = (short*)(wsb + (6u  << 20));
        short* ctx_bf = (short*)(wsb + (8u  << 20));
        short* qkv    = (short*)(wsb + (10u << 20));
        short* ff_bf  = (short*)(wsb + (10u << 20));
        short* emb_bf = (short*)(wsb + (18u << 20));
        const bool fastv = ws_size >= (52u << 20);

        const dim3 gQKV(QS / 64, Mv / 64);
        const dim3 gD(Dv / 64, Mv / 32);
        const dim3 gF(Fv / 128, Mv / 64);

        embed_kernel<<<Mv, blk, 0, stream>>>(x, emb, h);
        cvt_kernel<<<(Mv * Dv) / 1024, blk, 0, stream>>>(ctx, ctx_bf);
        if (fastv)
            cvt_kernel<<<(Vv * Dv) / 1024, blk, 0, stream>>>(emb, emb_bf);

        for (int i = 0; i < NBv; ++i) {
            const size_t wOff = (size_t)i * Dv * Dv;
            ln_kernel<<<Mv, blk, 0, stream>>>(h, ln1g + i * Dv, ln1b + i * Dv, y_bf);
            qkv_gemm<<<gQKV, blk, 0, stream>>>(y_bf, y_bf,
                                               wq_s + wOff, wk_s + wOff, wv_s + wOff, qkv);
            attn_mfma<<<gAttn, blk, 0, stream>>>(qkv, QS, qkv + 512, qkv + 1024, QS, ao_bf, 1);
            mgemm<32, 64, 64, 0, false, false, false><<<gD, blk, 0, stream>>>(
                ao_bf, wo_s + wOff, h, Mv, Dv, Dv, nullptr, h, 0);
            ln_kernel<<<Mv, blk, 0, stream>>>(h, ln2g + i * Dv, ln2b + i * Dv, y_bf);
            qkv_gemm<<<gQKV, blk, 0, stream>>>(y_bf, ctx_bf,
                                               wq_c + wOff, wk_c + wOff, wv_c + wOff, qkv);
            attn_mfma<<<gAttn, blk, 0, stream>>>(qkv, QS, qkv + 512, qkv + 1024, QS, ao_bf, 0);
            mgemm<32, 64, 64, 0, false, false, false><<<gD, blk, 0, stream>>>(
                ao_bf, wo_c + wOff, h, Mv, Dv, Dv, nullptr, h, 0);
            ln_kernel<<<Mv, blk, 0, stream>>>(h, ln3g + i * Dv, ln3b + i * Dv, y_bf);
            mgemm<64, 128, 64, 0, true, false, false><<<gF, blk, 0, stream>>>(
                y_bf, w1 + (size_t)i * Dv * Fv, ff_bf, Mv, Fv, Dv,
                b1 + (size_t)i * Fv, nullptr, 1);
            mgemm<32, 64, 64, 0, false, false, false><<<gD, blk, 0, stream>>>(
                ff_bf, w2 + (size_t)i * Fv * Dv, h, Mv, Dv, Fv,
                b2 + (size_t)i * Dv, h, 0);
        }

        ln_kernel<<<Mv, blk, 0, stream>>>(h, lnfg, lnfb, y_bf);
        if (fastv)
            mgemm<128, 128, 64, 2, false, true, false><<<gV, blk, 0, stream>>>(
                y_bf, (const float*)emb_bf, out, Mv, Vv, Dv, nullptr, nullptr, 0);
        else
            mgemm<128, 128, 64, 1, false, true, false><<<gV, blk, 0, stream>>>(
                y_bf, emb, out, Mv, Vv, Dv, nullptr, nullptr, 0);
    }
}